// Round 7
// baseline (393.855 us; speedup 1.0000x reference)
//
#include <hip/hip_runtime.h>

// N=50000, E=800000, Q=200000, d_in=64, h=128
// CSR-by-dest gather convs (wave-per-node); split-bf16 MFMA GEMMs;
// CSR fill via per-block reserved segments (LDS cursors, NO global atomics).

#define HB 128  // histogram / fill blocks

typedef __attribute__((ext_vector_type(8))) short short8;
typedef __attribute__((ext_vector_type(4))) float floatx4;

static __device__ __forceinline__ unsigned int f2bf(float v) {
    union { float f; unsigned int u; } c; c.f = v;
    unsigned int lsb = (c.u >> 16) & 1u;
    c.u += 0x7FFFu + lsb;                 // round-to-nearest-even
    return c.u >> 16;
}
static __device__ __forceinline__ float bf2f(unsigned int h) {
    union { float f; unsigned int u; } c; c.u = h << 16;
    return c.f;
}

// ---------- degree histogram (LDS-privatized, 16-bit packed) ----------
__global__ __launch_bounds__(256) void k_hist(const int* __restrict__ row,
                                              const int* __restrict__ col,
                                              unsigned int* __restrict__ hRow,
                                              unsigned int* __restrict__ hCol,
                                              int E, int W, int chunk) {
    __shared__ unsigned int lds[16384];
    int t = threadIdx.x, b = blockIdx.x;
    int e0 = b * chunk, e1 = min(E, e0 + chunk);
    for (int p = 0; p < 2; p++) {
        const int* idxArr = p ? col : row;
        unsigned int* outArr = p ? hCol : hRow;
        for (int base = 0; base < W; base += 16384) {
            int wcap = min(W - base, 16384);
            for (int i = t; i < wcap; i += 256) lds[i] = 0;
            __syncthreads();
            for (int e = e0 + t; e < e1; e += 256) {
                int idx = idxArr[e];
                int w = (idx >> 1) - base;
                if ((unsigned)w < (unsigned)wcap)
                    atomicAdd(&lds[w], 1u << ((idx & 1) * 16));
            }
            __syncthreads();
            for (int i = t; i < wcap; i += 256)
                outArr[(size_t)b * W + base + i] = lds[i];
            __syncthreads();
        }
    }
}

// Sum 16-bit lanes across HB partials; emit cntCol + dis, and REPLACE hCol
// partials with the exclusive prefix over blocks (packed 16-bit) for k_fill2.
__global__ __launch_bounds__(256) void k_reduce(const unsigned int* __restrict__ hRow,
                                                unsigned int* __restrict__ hCol,
                                                int* __restrict__ cntCol,
                                                float* __restrict__ dis,
                                                int N, int W) {
    int w = blockIdx.x * 256 + threadIdx.x;
    if (w >= W) return;
    unsigned int r0 = 0, r1 = 0, c0 = 0, c1 = 0;
#pragma unroll 8
    for (int b = 0; b < HB; b++) {
        size_t idx = (size_t)b * W + w;
        unsigned int hr = hRow[idx];
        unsigned int hc = hCol[idx];
        hCol[idx] = c0 | (c1 << 16);   // exclusive prefix over blocks
        r0 += hr & 0xFFFFu; r1 += hr >> 16;
        c0 += hc & 0xFFFFu; c1 += hc >> 16;
    }
    int n0 = 2 * w, n1 = 2 * w + 1;
    cntCol[n0] = (int)c0;
    dis[n0] = 1.0f / sqrtf((float)(r0 + 1));
    if (n1 < N) {
        cntCol[n1] = (int)c1;
        dis[n1] = 1.0f / sqrtf((float)(r1 + 1));
    }
}

// ---------- scan ----------
__global__ __launch_bounds__(256) void k_scan1(const int* __restrict__ cnt,
                                               int* __restrict__ offs,
                                               int* __restrict__ bsum, int N) {
    __shared__ int ts[256];
    int t = threadIdx.x;
    int base = blockIdx.x * 1024 + t * 4;
    int v0 = (base + 0 < N) ? cnt[base + 0] : 0;
    int v1 = (base + 1 < N) ? cnt[base + 1] : 0;
    int v2 = (base + 2 < N) ? cnt[base + 2] : 0;
    int v3 = (base + 3 < N) ? cnt[base + 3] : 0;
    int sum = v0 + v1 + v2 + v3;
    ts[t] = sum;
    __syncthreads();
    for (int off = 1; off < 256; off <<= 1) {
        int x = (t >= off) ? ts[t - off] : 0;
        __syncthreads();
        ts[t] += x;
        __syncthreads();
    }
    int e = ts[t] - sum;
    if (base + 0 < N) offs[base + 0] = e;
    if (base + 1 < N) offs[base + 1] = e + v0;
    if (base + 2 < N) offs[base + 2] = e + v0 + v1;
    if (base + 3 < N) offs[base + 3] = e + v0 + v1 + v2;
    if (t == 255) bsum[blockIdx.x] = ts[255];
}

__global__ __launch_bounds__(256) void k_scan2(int* __restrict__ bsum, int B) {
    __shared__ int ts[256];
    int t = threadIdx.x;
    int v = (t < B) ? bsum[t] : 0;
    ts[t] = v;
    __syncthreads();
    for (int off = 1; off < 256; off <<= 1) {
        int x = (t >= off) ? ts[t - off] : 0;
        __syncthreads();
        ts[t] += x;
        __syncthreads();
    }
    if (t < B) bsum[t] = ts[t] - v;
}

__global__ __launch_bounds__(256) void k_scan3(int* __restrict__ offs,
                                               const int* __restrict__ bsum,
                                               int N, int E) {
    int i = blockIdx.x * 256 + threadIdx.x;
    if (i < N) offs[i] = offs[i] + bsum[i >> 10];
    if (i == 0) offs[N] = E;
}

// ---------- CSR fill, atomic-free: per-block reserved segments ----------
// base[n] = offs[n] + prefix[b][n]; LDS cursors allocate within the segment.
__global__ __launch_bounds__(256) void k_fill2(const int* __restrict__ row,
                                               const int* __restrict__ col,
                                               const int* __restrict__ offs,
                                               const unsigned int* __restrict__ hCol,
                                               int* __restrict__ srcSorted,
                                               int E, int N, int W, int chunk) {
    __shared__ int base[16384];
    int t = threadIdx.x, b = blockIdx.x;
    int e0 = b * chunk, e1 = min(E, e0 + chunk);
    for (int n0 = 0; n0 < N; n0 += 16384) {
        int nCnt = min(16384, N - n0);
        for (int wl = t; wl * 2 < nCnt; wl += 256) {
            unsigned int pref = hCol[(size_t)b * W + (n0 >> 1) + wl];
            int nn = n0 + wl * 2;
            base[wl * 2] = offs[nn] + (int)(pref & 0xFFFFu);
            if (wl * 2 + 1 < nCnt)
                base[wl * 2 + 1] = offs[nn + 1] + (int)(pref >> 16);
        }
        __syncthreads();
        for (int e = e0 + t; e < e1; e += 256) {
            int c = col[e] - n0;
            if ((unsigned)c < (unsigned)nCnt) {
                int pos = atomicAdd(&base[c], 1);
                srcSorted[pos] = row[e];
            }
        }
        __syncthreads();
    }
}

// ---------- conv1 gather, wave-per-node: fp32 x in, split-bf16 agg1 out (d=64) ----------
__global__ __launch_bounds__(256) void k_gather1(const float* __restrict__ x,
                                                 const int* __restrict__ offs,
                                                 const int* __restrict__ srcs,
                                                 const float* __restrict__ dis,
                                                 unsigned short* __restrict__ aggHi,
                                                 unsigned short* __restrict__ aggLo,
                                                 int N) {
    int lane = threadIdx.x & 63;
    int node = __builtin_amdgcn_readfirstlane(blockIdx.x * 4 + (threadIdx.x >> 6));
    if (node >= N) return;
    int e = offs[node], eEnd = offs[node + 1];
    float dn = dis[node];
    float acc = x[(size_t)node * 64 + lane] * dn;
    for (; e < eEnd; e++) {
        int src = srcs[e];
        acc += x[(size_t)src * 64 + lane] * dis[src];
    }
    acc *= dn;
    unsigned int h = f2bf(acc);
    aggHi[(size_t)node * 64 + lane] = (unsigned short)h;
    aggLo[(size_t)node * 64 + lane] = (unsigned short)f2bf(acc - bf2f(h));
}

// ---------- conv2 gather, wave-per-node: bf16 h1 in, bf16 agg2 out (d=128) ----------
__global__ __launch_bounds__(256) void k_gather2(const unsigned short* __restrict__ s,
                                                 const int* __restrict__ offs,
                                                 const int* __restrict__ srcs,
                                                 const float* __restrict__ dis,
                                                 unsigned short* __restrict__ agg,
                                                 int N) {
    int lane = threadIdx.x & 63;
    int node = __builtin_amdgcn_readfirstlane(blockIdx.x * 4 + (threadIdx.x >> 6));
    if (node >= N) return;
    int e = offs[node], eEnd = offs[node + 1];
    float dn = dis[node];
    unsigned int w = *(const unsigned int*)(s + (size_t)node * 128 + lane * 2);
    float a0 = bf2f(w & 0xFFFFu), a1 = bf2f(w >> 16);
    for (; e < eEnd; e++) {
        int src = srcs[e];
        unsigned int v = *(const unsigned int*)(s + (size_t)src * 128 + lane * 2);
        a0 += bf2f(v & 0xFFFFu);
        a1 += bf2f(v >> 16);
    }
    unsigned int o = f2bf(a0 * dn) | (f2bf(a1 * dn) << 16);
    *(unsigned int*)(agg + (size_t)node * 128 + lane * 2) = o;
}

// ---------- fold + pack weights (split bf16, MFMA B-frag layout) ----------
__global__ __launch_bounds__(256) void k_fold(const float* __restrict__ W1,
                                              const float* __restrict__ W2,
                                              const float* __restrict__ Wc1,
                                              const float* __restrict__ b2,
                                              const float* __restrict__ bc1,
                                              unsigned short* __restrict__ UVhi,
                                              unsigned short* __restrict__ UVlo,
                                              unsigned short* __restrict__ W1hi,
                                              unsigned short* __restrict__ W1lo,
                                              float* __restrict__ buv) {
    __shared__ float w2row[128];
    int t = threadIdx.x, b = blockIdx.x;
    if (b < 128) {
        int k = b;
        int j = t & 127, half = t >> 7;
        int n = half * 128 + j;
        const float* wc = Wc1 + (size_t)half * 128 * 128 + j;
        if (t < 128) w2row[t] = W2[k * 128 + t];
        __syncthreads();
        float acc = 0.f;
#pragma unroll 8
        for (int m = 0; m < 128; m++) acc += w2row[m] * wc[(size_t)m * 128];
        int kstep = k >> 5, kl = k & 31, quad = kl >> 3, j8 = kl & 7;
        int nb = n >> 4, l = quad * 16 + (n & 15);
        int pidx = ((kstep * 16 + nb) * 64 + l) * 8 + j8;
        unsigned int h = f2bf(acc);
        UVhi[pidx] = (unsigned short)h;
        UVlo[pidx] = (unsigned short)f2bf(acc - bf2f(h));
    } else if (b == 128) {
        int j = t & 127, half = t >> 7;
        const float* wc = Wc1 + (size_t)half * 128 * 128 + j;
        float acc = half ? 0.f : bc1[j];
#pragma unroll 8
        for (int m = 0; m < 128; m++) acc += b2[m] * wc[(size_t)m * 128];
        buv[half * 128 + j] = acc;
    } else {
        int idx = (b - 129) * 256 + t;  // < 8192
        int k = idx >> 7, n = idx & 127;
        float v = W1[k * 128 + n];
        int kstep = k >> 5, kl = k & 31, quad = kl >> 3, j8 = kl & 7;
        int nb = n >> 4, l = quad * 16 + (n & 15);
        int pidx = ((kstep * 8 + nb) * 64 + l) * 8 + j8;
        unsigned int h = f2bf(v);
        W1hi[pidx] = (unsigned short)h;
        W1lo[pidx] = (unsigned short)f2bf(v - bf2f(h));
    }
}

// ---------- MFMA GEMM 1: h1b = bf16(relu(agg1 @ W1 + b1) * dis)  [K=64, 128 cols] ----------
__global__ __launch_bounds__(256) void k_mfma1(const unsigned short* __restrict__ Ahi,
                                               const unsigned short* __restrict__ Alo,
                                               const unsigned short* __restrict__ Bhi,
                                               const unsigned short* __restrict__ Blo,
                                               const float* __restrict__ b1,
                                               const float* __restrict__ dis,
                                               unsigned short* __restrict__ h1b, int N) {
    int lane = threadIdx.x & 63, wave = threadIdx.x >> 6;
    int mbase = blockIdx.x * 16;
    int ma = mbase + (lane & 15); if (ma >= N) ma = N - 1;
    int quad = lane >> 4;
    floatx4 acc[2] = {};
#pragma unroll
    for (int ks = 0; ks < 2; ks++) {
        short8 ahi = *(const short8*)(Ahi + (size_t)ma * 64 + ks * 32 + quad * 8);
        short8 alo = *(const short8*)(Alo + (size_t)ma * 64 + ks * 32 + quad * 8);
#pragma unroll
        for (int nt = 0; nt < 2; nt++) {
            int nb = wave * 2 + nt;
            short8 bhi = *(const short8*)(Bhi + ((ks * 8 + nb) * 64 + lane) * 8);
            short8 blo = *(const short8*)(Blo + ((ks * 8 + nb) * 64 + lane) * 8);
            acc[nt] = __builtin_amdgcn_mfma_f32_16x16x32_bf16(ahi, bhi, acc[nt], 0, 0, 0);
            acc[nt] = __builtin_amdgcn_mfma_f32_16x16x32_bf16(ahi, blo, acc[nt], 0, 0, 0);
            acc[nt] = __builtin_amdgcn_mfma_f32_16x16x32_bf16(alo, bhi, acc[nt], 0, 0, 0);
        }
    }
    int md = mbase + quad * 4;
#pragma unroll
    for (int nt = 0; nt < 2; nt++) {
        int n0 = (wave * 2 + nt) * 16 + (lane & 15);
        float bias = b1[n0];
#pragma unroll
        for (int r = 0; r < 4; r++) {
            int node = md + r;
            if (node < N)
                h1b[(size_t)node * 128 + n0] =
                    (unsigned short)f2bf(fmaxf(acc[nt][r] + bias, 0.f) * dis[node]);
        }
    }
}

// ---------- MFMA GEMM UV: [U|V] = agg2b @ Wfull + buv  [K=128, 256 cols, A bf16] ----------
__global__ __launch_bounds__(256) void k_mfmaUV(const unsigned short* __restrict__ A,
                                                const unsigned short* __restrict__ Bhi,
                                                const unsigned short* __restrict__ Blo,
                                                const float* __restrict__ buv,
                                                float* __restrict__ U,
                                                float* __restrict__ V, int N) {
    int lane = threadIdx.x & 63, wave = threadIdx.x >> 6;
    int mbase = blockIdx.x * 16;
    int ma = mbase + (lane & 15); if (ma >= N) ma = N - 1;
    int quad = lane >> 4;
    floatx4 acc[4] = {};
#pragma unroll
    for (int ks = 0; ks < 4; ks++) {
        short8 a = *(const short8*)(A + (size_t)ma * 128 + ks * 32 + quad * 8);
#pragma unroll
        for (int nt = 0; nt < 4; nt++) {
            int nb = wave * 4 + nt;
            short8 bhi = *(const short8*)(Bhi + ((ks * 16 + nb) * 64 + lane) * 8);
            short8 blo = *(const short8*)(Blo + ((ks * 16 + nb) * 64 + lane) * 8);
            acc[nt] = __builtin_amdgcn_mfma_f32_16x16x32_bf16(a, bhi, acc[nt], 0, 0, 0);
            acc[nt] = __builtin_amdgcn_mfma_f32_16x16x32_bf16(a, blo, acc[nt], 0, 0, 0);
        }
    }
    int md = mbase + quad * 4;
#pragma unroll
    for (int nt = 0; nt < 4; nt++) {
        int n0 = wave * 64 + nt * 16 + (lane & 15);
        float bias = buv[n0];
        float* dst = (n0 < 128) ? U : V;
        int cc = n0 & 127;
#pragma unroll
        for (int r = 0; r < 4; r++) {
            int node = md + r;
            if (node < N)
                dst[(size_t)node * 128 + cc] = acc[nt][r] + bias;
        }
    }
}

// ---------- head: out[q] = relu(U[src]+V[dst]) . Wc2 + bc2 ----------
__global__ __launch_bounds__(256) void k_head(const float* __restrict__ U,
                                              const float* __restrict__ V,
                                              const int* __restrict__ srcA,
                                              const int* __restrict__ dstA,
                                              const float* __restrict__ Wc2,
                                              const float* __restrict__ bc2,
                                              float* __restrict__ out, int Q) {
    int t = threadIdx.x;
    int q = blockIdx.x * 16 + (t >> 4);
    if (q >= Q) return;
    int l = t & 15;
    int s = srcA[q], d = dstA[q];
    const float4* u = (const float4*)(U + (size_t)s * 128 + l * 8);
    const float4* v = (const float4*)(V + (size_t)d * 128 + l * 8);
    const float4* w = (const float4*)(Wc2 + l * 8);
    float4 u0 = u[0], u1 = u[1];
    float4 v0 = v[0], v1 = v[1];
    float4 w0 = w[0], w1 = w[1];
    float acc = 0.f, z;
    z = fmaxf(u0.x + v0.x, 0.f); acc += z * w0.x;
    z = fmaxf(u0.y + v0.y, 0.f); acc += z * w0.y;
    z = fmaxf(u0.z + v0.z, 0.f); acc += z * w0.z;
    z = fmaxf(u0.w + v0.w, 0.f); acc += z * w0.w;
    z = fmaxf(u1.x + v1.x, 0.f); acc += z * w1.x;
    z = fmaxf(u1.y + v1.y, 0.f); acc += z * w1.y;
    z = fmaxf(u1.z + v1.z, 0.f); acc += z * w1.z;
    z = fmaxf(u1.w + v1.w, 0.f); acc += z * w1.w;
    acc += __shfl_xor(acc, 1);
    acc += __shfl_xor(acc, 2);
    acc += __shfl_xor(acc, 4);
    acc += __shfl_xor(acc, 8);
    if (l == 0) out[q] = acc + bc2[0];
}

extern "C" void kernel_launch(void* const* d_in, const int* in_sizes, int n_in,
                              void* d_out, int out_size, void* d_ws, size_t ws_size,
                              hipStream_t stream) {
    const float* x   = (const float*)d_in[0];
    const int*   ei  = (const int*)d_in[1];
    const int*   eli = (const int*)d_in[2];
    const float* W1  = (const float*)d_in[3];
    const float* b1  = (const float*)d_in[4];
    const float* W2  = (const float*)d_in[5];
    const float* b2  = (const float*)d_in[6];
    const float* Wc1 = (const float*)d_in[7];
    const float* bc1 = (const float*)d_in[8];
    const float* Wc2 = (const float*)d_in[9];
    const float* bc2 = (const float*)d_in[10];
    float* out = (float*)d_out;
    char* wsb = (char*)d_ws;

    const int N = in_sizes[0] / 64;
    const int E = in_sizes[1] / 2;
    const int Q = in_sizes[2] / 2;
    const int W = (N + 1) / 2;
    const int chunk = (E + HB - 1) / HB;

    // workspace layout (word offsets, 4B units); peak 17104128 words = 68.4 MB
    float* dis       = (float*)wsb;                                // 65536
    int*   offs      = (int*)wsb + 65536;                          // N+1
    int*   bsum      = (int*)wsb + 197120;                         // 256
    int*   cntCol    = (int*)wsb + 197376;                         // 65536
    float* buv       = (float*)wsb + 262912;                       // 256
    unsigned short* UVhi = (unsigned short*)((int*)wsb + 263168);  // 32768 us
    unsigned short* UVlo = (unsigned short*)((int*)wsb + 279552);
    unsigned short* W1hi = (unsigned short*)((int*)wsb + 295936);  // 8192 us
    unsigned short* W1lo = (unsigned short*)((int*)wsb + 300032);
    int*   srcSorted = (int*)wsb + 304128;                         // E -> 1104128
    // V spans [1104128, 7504128) and overlays dead agg1 + h1b at mfmaUV time
    float* V = (float*)wsb + 1104128;
    unsigned short* agg1hi = (unsigned short*)((int*)wsb + 1104128);  // N*64 us
    unsigned short* agg1lo = (unsigned short*)((int*)wsb + 2704128);
    unsigned short* h1b    = (unsigned short*)((int*)wsb + 4304128);  // N*128 us
    unsigned short* agg2b  = (unsigned short*)((int*)wsb + 7504128);  // N*128 us -> 10704128
    // U spans [10704128, 17104128) and overlays hist partials (dead after k_fill2)
    float* U = (float*)wsb + 10704128;
    unsigned int* hRow = (unsigned int*)wsb + 10704128;            // HB*W -> 13904128
    unsigned int* hCol = (unsigned int*)wsb + 13904128;            // HB*W -> 17104128

    const int* row  = ei;
    const int* col  = ei + E;
    const int* srcA = eli;
    const int* dstA = eli + Q;

    const int scanB = (N + 1023) / 1024;

    k_hist<<<HB, 256, 0, stream>>>(row, col, hRow, hCol, E, W, chunk);
    k_reduce<<<(W + 255) / 256, 256, 0, stream>>>(hRow, hCol, cntCol, dis, N, W);
    k_scan1<<<scanB, 256, 0, stream>>>(cntCol, offs, bsum, N);
    k_scan2<<<1, 256, 0, stream>>>(bsum, scanB);
    k_scan3<<<(N + 255) / 256, 256, 0, stream>>>(offs, bsum, N, E);
    k_fill2<<<HB, 256, 0, stream>>>(row, col, offs, hCol, srcSorted, E, N, W, chunk);
    k_fold<<<161, 256, 0, stream>>>(W1, W2, Wc1, b2, bc1, UVhi, UVlo, W1hi, W1lo, buv);
    k_gather1<<<(N + 3) / 4, 256, 0, stream>>>(x, offs, srcSorted, dis, agg1hi, agg1lo, N);
    k_mfma1<<<(N + 15) / 16, 256, 0, stream>>>(agg1hi, agg1lo, W1hi, W1lo, b1, dis, h1b, N);
    k_gather2<<<(N + 3) / 4, 256, 0, stream>>>(h1b, offs, srcSorted, dis, agg2b, N);
    k_mfmaUV<<<(N + 15) / 16, 256, 0, stream>>>(agg2b, UVhi, UVlo, buv, U, V, N);
    k_head<<<(Q + 15) / 16, 256, 0, stream>>>(U, V, srcA, dstA, Wc2, bc2, out, Q);
}

// Round 8
// 326.066 us; speedup vs baseline: 1.2079x; 1.2079x over previous
//
#include <hip/hip_runtime.h>

// N=50000, E=800000, Q=200000, d_in=64, h=128
// CSR-by-dest gather convs (16 lanes/node, vectorized); split-bf16 MFMA GEMMs;
// atomic-free CSR fill via per-(block,window) reserved segments, 2D grid.

#define HB 128   // histogram / fill chunks
#define NWIN 16384  // fill node-window size (64KB LDS of int cursors)

typedef __attribute__((ext_vector_type(8))) short short8;
typedef __attribute__((ext_vector_type(4))) float floatx4;

static __device__ __forceinline__ unsigned int f2bf(float v) {
    union { float f; unsigned int u; } c; c.f = v;
    unsigned int lsb = (c.u >> 16) & 1u;
    c.u += 0x7FFFu + lsb;                 // round-to-nearest-even
    return c.u >> 16;
}
static __device__ __forceinline__ float bf2f(unsigned int h) {
    union { float f; unsigned int u; } c; c.u = h << 16;
    return c.f;
}
static __device__ __forceinline__ void store_split4(float4 v,
                                                    unsigned short* hi,
                                                    unsigned short* lo) {
    unsigned int h0 = f2bf(v.x), h1 = f2bf(v.y), h2 = f2bf(v.z), h3 = f2bf(v.w);
    uint2 hw; hw.x = h0 | (h1 << 16); hw.y = h2 | (h3 << 16);
    unsigned int l0 = f2bf(v.x - bf2f(h0)), l1 = f2bf(v.y - bf2f(h1));
    unsigned int l2 = f2bf(v.z - bf2f(h2)), l3 = f2bf(v.w - bf2f(h3));
    uint2 lw; lw.x = l0 | (l1 << 16); lw.y = l2 | (l3 << 16);
    *(uint2*)hi = hw;
    *(uint2*)lo = lw;
}

// ---------- degree histogram (LDS-privatized, 16-bit packed) ----------
__global__ __launch_bounds__(256) void k_hist(const int* __restrict__ row,
                                              const int* __restrict__ col,
                                              unsigned int* __restrict__ hRow,
                                              unsigned int* __restrict__ hCol,
                                              int E, int W, int chunk) {
    __shared__ unsigned int lds[16384];
    int t = threadIdx.x, b = blockIdx.x;
    int e0 = b * chunk, e1 = min(E, e0 + chunk);
    for (int p = 0; p < 2; p++) {
        const int* idxArr = p ? col : row;
        unsigned int* outArr = p ? hCol : hRow;
        for (int base = 0; base < W; base += 16384) {
            int wcap = min(W - base, 16384);
            for (int i = t; i < wcap; i += 256) lds[i] = 0;
            __syncthreads();
            for (int e = e0 + t; e < e1; e += 256) {
                int idx = idxArr[e];
                int w = (idx >> 1) - base;
                if ((unsigned)w < (unsigned)wcap)
                    atomicAdd(&lds[w], 1u << ((idx & 1) * 16));
            }
            __syncthreads();
            for (int i = t; i < wcap; i += 256)
                outArr[(size_t)b * W + base + i] = lds[i];
            __syncthreads();
        }
    }
}

// Sum 16-bit lanes across HB partials; emit cntCol + dis, and REPLACE hCol
// partials with the exclusive prefix over blocks (packed 16-bit) for k_fill3.
__global__ __launch_bounds__(256) void k_reduce(const unsigned int* __restrict__ hRow,
                                                unsigned int* __restrict__ hCol,
                                                int* __restrict__ cntCol,
                                                float* __restrict__ dis,
                                                int N, int W) {
    int w = blockIdx.x * 256 + threadIdx.x;
    if (w >= W) return;
    unsigned int r0 = 0, r1 = 0, c0 = 0, c1 = 0;
#pragma unroll 8
    for (int b = 0; b < HB; b++) {
        size_t idx = (size_t)b * W + w;
        unsigned int hr = hRow[idx];
        unsigned int hc = hCol[idx];
        hCol[idx] = c0 | (c1 << 16);   // exclusive prefix over blocks
        r0 += hr & 0xFFFFu; r1 += hr >> 16;
        c0 += hc & 0xFFFFu; c1 += hc >> 16;
    }
    int n0 = 2 * w, n1 = 2 * w + 1;
    cntCol[n0] = (int)c0;
    dis[n0] = 1.0f / sqrtf((float)(r0 + 1));
    if (n1 < N) {
        cntCol[n1] = (int)c1;
        dis[n1] = 1.0f / sqrtf((float)(r1 + 1));
    }
}

// ---------- scan ----------
__global__ __launch_bounds__(256) void k_scan1(const int* __restrict__ cnt,
                                               int* __restrict__ offs,
                                               int* __restrict__ bsum, int N) {
    __shared__ int ts[256];
    int t = threadIdx.x;
    int base = blockIdx.x * 1024 + t * 4;
    int v0 = (base + 0 < N) ? cnt[base + 0] : 0;
    int v1 = (base + 1 < N) ? cnt[base + 1] : 0;
    int v2 = (base + 2 < N) ? cnt[base + 2] : 0;
    int v3 = (base + 3 < N) ? cnt[base + 3] : 0;
    int sum = v0 + v1 + v2 + v3;
    ts[t] = sum;
    __syncthreads();
    for (int off = 1; off < 256; off <<= 1) {
        int x = (t >= off) ? ts[t - off] : 0;
        __syncthreads();
        ts[t] += x;
        __syncthreads();
    }
    int e = ts[t] - sum;
    if (base + 0 < N) offs[base + 0] = e;
    if (base + 1 < N) offs[base + 1] = e + v0;
    if (base + 2 < N) offs[base + 2] = e + v0 + v1;
    if (base + 3 < N) offs[base + 3] = e + v0 + v1 + v2;
    if (t == 255) bsum[blockIdx.x] = ts[255];
}

__global__ __launch_bounds__(256) void k_scan2(int* __restrict__ bsum, int B) {
    __shared__ int ts[256];
    int t = threadIdx.x;
    int v = (t < B) ? bsum[t] : 0;
    ts[t] = v;
    __syncthreads();
    for (int off = 1; off < 256; off <<= 1) {
        int x = (t >= off) ? ts[t - off] : 0;
        __syncthreads();
        ts[t] += x;
        __syncthreads();
    }
    if (t < B) bsum[t] = ts[t] - v;
}

__global__ __launch_bounds__(256) void k_scan3(int* __restrict__ offs,
                                               const int* __restrict__ bsum,
                                               int N, int E) {
    int i = blockIdx.x * 256 + threadIdx.x;
    if (i < N) offs[i] = offs[i] + bsum[i >> 10];
    if (i == 0) offs[N] = E;
}

// ---------- CSR fill, atomic-free, 2D grid: x = edge chunk, y = node window ----------
__global__ __launch_bounds__(256) void k_fill3(const int* __restrict__ row,
                                               const int* __restrict__ col,
                                               const int* __restrict__ offs,
                                               const unsigned int* __restrict__ hCol,
                                               int* __restrict__ srcSorted,
                                               int E, int N, int W, int chunk) {
    __shared__ int base[NWIN];
    int t = threadIdx.x, b = blockIdx.x;
    int n0 = blockIdx.y * NWIN;
    int nCnt = min(NWIN, N - n0);
    int e0 = b * chunk, e1 = min(E, e0 + chunk);
    for (int wl = t; wl * 2 < nCnt; wl += 256) {
        unsigned int pref = hCol[(size_t)b * W + (n0 >> 1) + wl];
        int nn = n0 + wl * 2;
        base[wl * 2] = offs[nn] + (int)(pref & 0xFFFFu);
        if (wl * 2 + 1 < nCnt)
            base[wl * 2 + 1] = offs[nn + 1] + (int)(pref >> 16);
    }
    __syncthreads();
    for (int e = e0 + t; e < e1; e += 256) {
        int c = col[e] - n0;
        if ((unsigned)c < (unsigned)nCnt) {
            int pos = atomicAdd(&base[c], 1);
            srcSorted[pos] = row[e];
        }
    }
}

// ---------- conv1 gather: fp32 x in, split-bf16 agg1 out (d=64, 16 lanes/node) ----------
__global__ __launch_bounds__(256) void k_gather1(const float* __restrict__ s,
                                                 const int* __restrict__ offs,
                                                 const int* __restrict__ srcs,
                                                 const float* __restrict__ dis,
                                                 unsigned short* __restrict__ aggHi,
                                                 unsigned short* __restrict__ aggLo,
                                                 int N) {
    int tid = blockIdx.x * 256 + threadIdx.x;
    int node = tid >> 4;
    if (node >= N) return;
    int c4 = (tid & 15) * 4;
    int e = offs[node], eEnd = offs[node + 1];
    float dn = dis[node];
    float4 acc = *(const float4*)(s + (size_t)node * 64 + c4);
    acc.x *= dn; acc.y *= dn; acc.z *= dn; acc.w *= dn;
    int srcNext = (e < eEnd) ? srcs[e] : 0;
    float dNext = dis[srcNext];
    while (e < eEnd) {
        int src = srcNext;
        float dsrc = dNext;
        e++;
        srcNext = (e < eEnd) ? srcs[e] : 0;
        dNext = dis[srcNext];
        float4 v = *(const float4*)(s + (size_t)src * 64 + c4);
        acc.x += v.x * dsrc; acc.y += v.y * dsrc;
        acc.z += v.z * dsrc; acc.w += v.w * dsrc;
    }
    acc.x *= dn; acc.y *= dn; acc.z *= dn; acc.w *= dn;
    store_split4(acc, aggHi + (size_t)node * 64 + c4, aggLo + (size_t)node * 64 + c4);
}

// ---------- conv2 gather: bf16 h1 in, bf16 agg2 out (d=128, 16 lanes/node) ----------
__global__ __launch_bounds__(256) void k_gather2(const unsigned short* __restrict__ s,
                                                 const int* __restrict__ offs,
                                                 const int* __restrict__ srcs,
                                                 const float* __restrict__ dis,
                                                 unsigned short* __restrict__ agg,
                                                 int N) {
    int tid = blockIdx.x * 256 + threadIdx.x;
    int node = tid >> 4;
    if (node >= N) return;
    int c8 = (tid & 15) * 8;  // bf16 element offset; 16 B per thread
    int e = offs[node], eEnd = offs[node + 1];
    float dn = dis[node];
    uint4 w = *(const uint4*)(s + (size_t)node * 128 + c8);
    float a0 = bf2f(w.x & 0xFFFF), a1 = bf2f(w.x >> 16);
    float a2 = bf2f(w.y & 0xFFFF), a3 = bf2f(w.y >> 16);
    float a4 = bf2f(w.z & 0xFFFF), a5 = bf2f(w.z >> 16);
    float a6 = bf2f(w.w & 0xFFFF), a7 = bf2f(w.w >> 16);
    int srcNext = (e < eEnd) ? srcs[e] : 0;
    while (e < eEnd) {
        int src = srcNext;
        e++;
        srcNext = (e < eEnd) ? srcs[e] : 0;
        uint4 v = *(const uint4*)(s + (size_t)src * 128 + c8);
        a0 += bf2f(v.x & 0xFFFF); a1 += bf2f(v.x >> 16);
        a2 += bf2f(v.y & 0xFFFF); a3 += bf2f(v.y >> 16);
        a4 += bf2f(v.z & 0xFFFF); a5 += bf2f(v.z >> 16);
        a6 += bf2f(v.w & 0xFFFF); a7 += bf2f(v.w >> 16);
    }
    uint4 o;
    o.x = f2bf(a0 * dn) | (f2bf(a1 * dn) << 16);
    o.y = f2bf(a2 * dn) | (f2bf(a3 * dn) << 16);
    o.z = f2bf(a4 * dn) | (f2bf(a5 * dn) << 16);
    o.w = f2bf(a6 * dn) | (f2bf(a7 * dn) << 16);
    *(uint4*)(agg + (size_t)node * 128 + c8) = o;
}

// ---------- fold + pack weights (split bf16, MFMA B-frag layout) ----------
__global__ __launch_bounds__(256) void k_fold(const float* __restrict__ W1,
                                              const float* __restrict__ W2,
                                              const float* __restrict__ Wc1,
                                              const float* __restrict__ b2,
                                              const float* __restrict__ bc1,
                                              unsigned short* __restrict__ UVhi,
                                              unsigned short* __restrict__ UVlo,
                                              unsigned short* __restrict__ W1hi,
                                              unsigned short* __restrict__ W1lo,
                                              float* __restrict__ buv) {
    __shared__ float w2row[128];
    int t = threadIdx.x, b = blockIdx.x;
    if (b < 128) {
        int k = b;
        int j = t & 127, half = t >> 7;
        int n = half * 128 + j;
        const float* wc = Wc1 + (size_t)half * 128 * 128 + j;
        if (t < 128) w2row[t] = W2[k * 128 + t];
        __syncthreads();
        float acc = 0.f;
#pragma unroll 8
        for (int m = 0; m < 128; m++) acc += w2row[m] * wc[(size_t)m * 128];
        int kstep = k >> 5, kl = k & 31, quad = kl >> 3, j8 = kl & 7;
        int nb = n >> 4, l = quad * 16 + (n & 15);
        int pidx = ((kstep * 16 + nb) * 64 + l) * 8 + j8;
        unsigned int h = f2bf(acc);
        UVhi[pidx] = (unsigned short)h;
        UVlo[pidx] = (unsigned short)f2bf(acc - bf2f(h));
    } else if (b == 128) {
        int j = t & 127, half = t >> 7;
        const float* wc = Wc1 + (size_t)half * 128 * 128 + j;
        float acc = half ? 0.f : bc1[j];
#pragma unroll 8
        for (int m = 0; m < 128; m++) acc += b2[m] * wc[(size_t)m * 128];
        buv[half * 128 + j] = acc;
    } else {
        int idx = (b - 129) * 256 + t;  // < 8192
        int k = idx >> 7, n = idx & 127;
        float v = W1[k * 128 + n];
        int kstep = k >> 5, kl = k & 31, quad = kl >> 3, j8 = kl & 7;
        int nb = n >> 4, l = quad * 16 + (n & 15);
        int pidx = ((kstep * 8 + nb) * 64 + l) * 8 + j8;
        unsigned int h = f2bf(v);
        W1hi[pidx] = (unsigned short)h;
        W1lo[pidx] = (unsigned short)f2bf(v - bf2f(h));
    }
}

// ---------- MFMA GEMM 1: h1b = bf16(relu(agg1 @ W1 + b1) * dis)  [K=64, 128 cols] ----------
__global__ __launch_bounds__(256) void k_mfma1(const unsigned short* __restrict__ Ahi,
                                               const unsigned short* __restrict__ Alo,
                                               const unsigned short* __restrict__ Bhi,
                                               const unsigned short* __restrict__ Blo,
                                               const float* __restrict__ b1,
                                               const float* __restrict__ dis,
                                               unsigned short* __restrict__ h1b, int N) {
    int lane = threadIdx.x & 63, wave = threadIdx.x >> 6;
    int mbase = blockIdx.x * 16;
    int ma = mbase + (lane & 15); if (ma >= N) ma = N - 1;
    int quad = lane >> 4;
    floatx4 acc[2] = {};
#pragma unroll
    for (int ks = 0; ks < 2; ks++) {
        short8 ahi = *(const short8*)(Ahi + (size_t)ma * 64 + ks * 32 + quad * 8);
        short8 alo = *(const short8*)(Alo + (size_t)ma * 64 + ks * 32 + quad * 8);
#pragma unroll
        for (int nt = 0; nt < 2; nt++) {
            int nb = wave * 2 + nt;
            short8 bhi = *(const short8*)(Bhi + ((ks * 8 + nb) * 64 + lane) * 8);
            short8 blo = *(const short8*)(Blo + ((ks * 8 + nb) * 64 + lane) * 8);
            acc[nt] = __builtin_amdgcn_mfma_f32_16x16x32_bf16(ahi, bhi, acc[nt], 0, 0, 0);
            acc[nt] = __builtin_amdgcn_mfma_f32_16x16x32_bf16(ahi, blo, acc[nt], 0, 0, 0);
            acc[nt] = __builtin_amdgcn_mfma_f32_16x16x32_bf16(alo, bhi, acc[nt], 0, 0, 0);
        }
    }
    int md = mbase + quad * 4;
#pragma unroll
    for (int nt = 0; nt < 2; nt++) {
        int n0 = (wave * 2 + nt) * 16 + (lane & 15);
        float bias = b1[n0];
#pragma unroll
        for (int r = 0; r < 4; r++) {
            int node = md + r;
            if (node < N)
                h1b[(size_t)node * 128 + n0] =
                    (unsigned short)f2bf(fmaxf(acc[nt][r] + bias, 0.f) * dis[node]);
        }
    }
}

// ---------- MFMA GEMM UV: [U|V] = agg2b @ Wfull + buv  [K=128, 256 cols, A bf16] ----------
__global__ __launch_bounds__(256) void k_mfmaUV(const unsigned short* __restrict__ A,
                                                const unsigned short* __restrict__ Bhi,
                                                const unsigned short* __restrict__ Blo,
                                                const float* __restrict__ buv,
                                                float* __restrict__ U,
                                                float* __restrict__ V, int N) {
    int lane = threadIdx.x & 63, wave = threadIdx.x >> 6;
    int mbase = blockIdx.x * 16;
    int ma = mbase + (lane & 15); if (ma >= N) ma = N - 1;
    int quad = lane >> 4;
    floatx4 acc[4] = {};
#pragma unroll
    for (int ks = 0; ks < 4; ks++) {
        short8 a = *(const short8*)(A + (size_t)ma * 128 + ks * 32 + quad * 8);
#pragma unroll
        for (int nt = 0; nt < 4; nt++) {
            int nb = wave * 4 + nt;
            short8 bhi = *(const short8*)(Bhi + ((ks * 16 + nb) * 64 + lane) * 8);
            short8 blo = *(const short8*)(Blo + ((ks * 16 + nb) * 64 + lane) * 8);
            acc[nt] = __builtin_amdgcn_mfma_f32_16x16x32_bf16(a, bhi, acc[nt], 0, 0, 0);
            acc[nt] = __builtin_amdgcn_mfma_f32_16x16x32_bf16(a, blo, acc[nt], 0, 0, 0);
        }
    }
    int md = mbase + quad * 4;
#pragma unroll
    for (int nt = 0; nt < 4; nt++) {
        int n0 = wave * 64 + nt * 16 + (lane & 15);
        float bias = buv[n0];
        float* dst = (n0 < 128) ? U : V;
        int cc = n0 & 127;
#pragma unroll
        for (int r = 0; r < 4; r++) {
            int node = md + r;
            if (node < N)
                dst[(size_t)node * 128 + cc] = acc[nt][r] + bias;
        }
    }
}

// ---------- head: out[q] = relu(U[src]+V[dst]) . Wc2 + bc2 ----------
__global__ __launch_bounds__(256) void k_head(const float* __restrict__ U,
                                              const float* __restrict__ V,
                                              const int* __restrict__ srcA,
                                              const int* __restrict__ dstA,
                                              const float* __restrict__ Wc2,
                                              const float* __restrict__ bc2,
                                              float* __restrict__ out, int Q) {
    int t = threadIdx.x;
    int q = blockIdx.x * 16 + (t >> 4);
    if (q >= Q) return;
    int l = t & 15;
    int s = srcA[q], d = dstA[q];
    const float4* u = (const float4*)(U + (size_t)s * 128 + l * 8);
    const float4* v = (const float4*)(V + (size_t)d * 128 + l * 8);
    const float4* w = (const float4*)(Wc2 + l * 8);
    float4 u0 = u[0], u1 = u[1];
    float4 v0 = v[0], v1 = v[1];
    float4 w0 = w[0], w1 = w[1];
    float acc = 0.f, z;
    z = fmaxf(u0.x + v0.x, 0.f); acc += z * w0.x;
    z = fmaxf(u0.y + v0.y, 0.f); acc += z * w0.y;
    z = fmaxf(u0.z + v0.z, 0.f); acc += z * w0.z;
    z = fmaxf(u0.w + v0.w, 0.f); acc += z * w0.w;
    z = fmaxf(u1.x + v1.x, 0.f); acc += z * w1.x;
    z = fmaxf(u1.y + v1.y, 0.f); acc += z * w1.y;
    z = fmaxf(u1.z + v1.z, 0.f); acc += z * w1.z;
    z = fmaxf(u1.w + v1.w, 0.f); acc += z * w1.w;
    acc += __shfl_xor(acc, 1);
    acc += __shfl_xor(acc, 2);
    acc += __shfl_xor(acc, 4);
    acc += __shfl_xor(acc, 8);
    if (l == 0) out[q] = acc + bc2[0];
}

extern "C" void kernel_launch(void* const* d_in, const int* in_sizes, int n_in,
                              void* d_out, int out_size, void* d_ws, size_t ws_size,
                              hipStream_t stream) {
    const float* x   = (const float*)d_in[0];
    const int*   ei  = (const int*)d_in[1];
    const int*   eli = (const int*)d_in[2];
    const float* W1  = (const float*)d_in[3];
    const float* b1  = (const float*)d_in[4];
    const float* W2  = (const float*)d_in[5];
    const float* b2  = (const float*)d_in[6];
    const float* Wc1 = (const float*)d_in[7];
    const float* bc1 = (const float*)d_in[8];
    const float* Wc2 = (const float*)d_in[9];
    const float* bc2 = (const float*)d_in[10];
    float* out = (float*)d_out;
    char* wsb = (char*)d_ws;

    const int N = in_sizes[0] / 64;
    const int E = in_sizes[1] / 2;
    const int Q = in_sizes[2] / 2;
    const int W = (N + 1) / 2;
    const int chunk = (E + HB - 1) / HB;
    const int nPass = (N + NWIN - 1) / NWIN;

    // workspace layout (word offsets, 4B units); peak 17104128 words = 68.4 MB
    float* dis       = (float*)wsb;                                // 65536
    int*   offs      = (int*)wsb + 65536;                          // N+1
    int*   bsum      = (int*)wsb + 197120;                         // 256
    int*   cntCol    = (int*)wsb + 197376;                         // 65536
    float* buv       = (float*)wsb + 262912;                       // 256
    unsigned short* UVhi = (unsigned short*)((int*)wsb + 263168);  // 32768 us
    unsigned short* UVlo = (unsigned short*)((int*)wsb + 279552);
    unsigned short* W1hi = (unsigned short*)((int*)wsb + 295936);  // 8192 us
    unsigned short* W1lo = (unsigned short*)((int*)wsb + 300032);
    int*   srcSorted = (int*)wsb + 304128;                         // E -> 1104128
    // V spans [1104128, 7504128) and overlays dead agg1 + h1b at mfmaUV time
    float* V = (float*)wsb + 1104128;
    unsigned short* agg1hi = (unsigned short*)((int*)wsb + 1104128);  // N*64 us
    unsigned short* agg1lo = (unsigned short*)((int*)wsb + 2704128);
    unsigned short* h1b    = (unsigned short*)((int*)wsb + 4304128);  // N*128 us
    unsigned short* agg2b  = (unsigned short*)((int*)wsb + 7504128);  // N*128 us -> 10704128
    // U spans [10704128, 17104128) and overlays hist partials (dead after k_fill3)
    float* U = (float*)wsb + 10704128;
    unsigned int* hRow = (unsigned int*)wsb + 10704128;            // HB*W -> 13904128
    unsigned int* hCol = (unsigned int*)wsb + 13904128;            // HB*W -> 17104128

    const int* row  = ei;
    const int* col  = ei + E;
    const int* srcA = eli;
    const int* dstA = eli + Q;

    const int scanB = (N + 1023) / 1024;

    k_hist<<<HB, 256, 0, stream>>>(row, col, hRow, hCol, E, W, chunk);
    k_reduce<<<(W + 255) / 256, 256, 0, stream>>>(hRow, hCol, cntCol, dis, N, W);
    k_scan1<<<scanB, 256, 0, stream>>>(cntCol, offs, bsum, N);
    k_scan2<<<1, 256, 0, stream>>>(bsum, scanB);
    k_scan3<<<(N + 255) / 256, 256, 0, stream>>>(offs, bsum, N, E);
    k_fill3<<<dim3(HB, nPass), 256, 0, stream>>>(row, col, offs, hCol, srcSorted, E, N, W, chunk);
    k_fold<<<161, 256, 0, stream>>>(W1, W2, Wc1, b2, bc1, UVhi, UVlo, W1hi, W1lo, buv);
    k_gather1<<<((size_t)N * 16 + 255) / 256, 256, 0, stream>>>(
        x, offs, srcSorted, dis, agg1hi, agg1lo, N);
    k_mfma1<<<(N + 15) / 16, 256, 0, stream>>>(agg1hi, agg1lo, W1hi, W1lo, b1, dis, h1b, N);
    k_gather2<<<((size_t)N * 16 + 255) / 256, 256, 0, stream>>>(
        h1b, offs, srcSorted, dis, agg2b, N);
    k_mfmaUV<<<(N + 15) / 16, 256, 0, stream>>>(agg2b, UVhi, UVlo, buv, U, V, N);
    k_head<<<(Q + 15) / 16, 256, 0, stream>>>(U, V, srcA, dstA, Wc2, bc2, out, Q);
}

// Round 9
// 306.177 us; speedup vs baseline: 1.2864x; 1.0650x over previous
//
#include <hip/hip_runtime.h>

// N=50000, E=800000, Q=200000, d_in=64, h=128
// CSR-by-dest gather convs (16 lanes/node); split-bf16 MFMA GEMMs (B register-
// resident, 64 rows/block); atomic-free CSR fill; 2D-grid histogram.

#define HB 128   // histogram / fill chunks
#define NWIN 16384  // node-window size (64KB LDS)

typedef __attribute__((ext_vector_type(8))) short short8;
typedef __attribute__((ext_vector_type(4))) float floatx4;

static __device__ __forceinline__ unsigned int f2bf(float v) {
    union { float f; unsigned int u; } c; c.f = v;
    unsigned int lsb = (c.u >> 16) & 1u;
    c.u += 0x7FFFu + lsb;                 // round-to-nearest-even
    return c.u >> 16;
}
static __device__ __forceinline__ float bf2f(unsigned int h) {
    union { float f; unsigned int u; } c; c.u = h << 16;
    return c.f;
}
static __device__ __forceinline__ void store_split4(float4 v,
                                                    unsigned short* hi,
                                                    unsigned short* lo) {
    unsigned int h0 = f2bf(v.x), h1 = f2bf(v.y), h2 = f2bf(v.z), h3 = f2bf(v.w);
    uint2 hw; hw.x = h0 | (h1 << 16); hw.y = h2 | (h3 << 16);
    unsigned int l0 = f2bf(v.x - bf2f(h0)), l1 = f2bf(v.y - bf2f(h1));
    unsigned int l2 = f2bf(v.z - bf2f(h2)), l3 = f2bf(v.w - bf2f(h3));
    uint2 lw; lw.x = l0 | (l1 << 16); lw.y = l2 | (l3 << 16);
    *(uint2*)hi = hw;
    *(uint2*)lo = lw;
}

// ---------- degree histogram: 2D grid (edge-chunk, array x window) ----------
__global__ __launch_bounds__(256) void k_hist(const int* __restrict__ row,
                                              const int* __restrict__ col,
                                              unsigned int* __restrict__ hRow,
                                              unsigned int* __restrict__ hCol,
                                              int E, int W, int chunk) {
    __shared__ unsigned int lds[NWIN];
    int t = threadIdx.x, b = blockIdx.x;
    int p = blockIdx.y >> 1;        // 0 = row array, 1 = col array
    int win = blockIdx.y & 1;       // word-window index
    int base = win * NWIN;
    int wcap = min(W - base, NWIN);
    if (wcap <= 0) return;
    const int* idxArr = p ? col : row;
    unsigned int* outArr = p ? hCol : hRow;
    int e0 = b * chunk, e1 = min(E, e0 + chunk);
    for (int i = t; i < wcap; i += 256) lds[i] = 0;
    __syncthreads();
    for (int e = e0 + t; e < e1; e += 256) {
        int idx = idxArr[e];
        int w = (idx >> 1) - base;
        if ((unsigned)w < (unsigned)wcap)
            atomicAdd(&lds[w], 1u << ((idx & 1) * 16));
    }
    __syncthreads();
    for (int i = t; i < wcap; i += 256)
        outArr[(size_t)b * W + base + i] = lds[i];
}

// Sum 16-bit lanes across HB partials; emit cntCol + dis, and REPLACE hCol
// partials with the exclusive prefix over blocks (packed 16-bit) for k_fill3.
__global__ __launch_bounds__(256) void k_reduce(const unsigned int* __restrict__ hRow,
                                                unsigned int* __restrict__ hCol,
                                                int* __restrict__ cntCol,
                                                float* __restrict__ dis,
                                                int N, int W) {
    int w = blockIdx.x * 256 + threadIdx.x;
    if (w >= W) return;
    unsigned int r0 = 0, r1 = 0, c0 = 0, c1 = 0;
#pragma unroll 8
    for (int b = 0; b < HB; b++) {
        size_t idx = (size_t)b * W + w;
        unsigned int hr = hRow[idx];
        unsigned int hc = hCol[idx];
        hCol[idx] = c0 | (c1 << 16);   // exclusive prefix over blocks
        r0 += hr & 0xFFFFu; r1 += hr >> 16;
        c0 += hc & 0xFFFFu; c1 += hc >> 16;
    }
    int n0 = 2 * w, n1 = 2 * w + 1;
    cntCol[n0] = (int)c0;
    dis[n0] = 1.0f / sqrtf((float)(r0 + 1));
    if (n1 < N) {
        cntCol[n1] = (int)c1;
        dis[n1] = 1.0f / sqrtf((float)(r1 + 1));
    }
}

// ---------- scan ----------
__global__ __launch_bounds__(256) void k_scan1(const int* __restrict__ cnt,
                                               int* __restrict__ offs,
                                               int* __restrict__ bsum, int N) {
    __shared__ int ts[256];
    int t = threadIdx.x;
    int base = blockIdx.x * 1024 + t * 4;
    int v0 = (base + 0 < N) ? cnt[base + 0] : 0;
    int v1 = (base + 1 < N) ? cnt[base + 1] : 0;
    int v2 = (base + 2 < N) ? cnt[base + 2] : 0;
    int v3 = (base + 3 < N) ? cnt[base + 3] : 0;
    int sum = v0 + v1 + v2 + v3;
    ts[t] = sum;
    __syncthreads();
    for (int off = 1; off < 256; off <<= 1) {
        int x = (t >= off) ? ts[t - off] : 0;
        __syncthreads();
        ts[t] += x;
        __syncthreads();
    }
    int e = ts[t] - sum;
    if (base + 0 < N) offs[base + 0] = e;
    if (base + 1 < N) offs[base + 1] = e + v0;
    if (base + 2 < N) offs[base + 2] = e + v0 + v1;
    if (base + 3 < N) offs[base + 3] = e + v0 + v1 + v2;
    if (t == 255) bsum[blockIdx.x] = ts[255];
}

__global__ __launch_bounds__(256) void k_scan2(int* __restrict__ bsum, int B) {
    __shared__ int ts[256];
    int t = threadIdx.x;
    int v = (t < B) ? bsum[t] : 0;
    ts[t] = v;
    __syncthreads();
    for (int off = 1; off < 256; off <<= 1) {
        int x = (t >= off) ? ts[t - off] : 0;
        __syncthreads();
        ts[t] += x;
        __syncthreads();
    }
    if (t < B) bsum[t] = ts[t] - v;
}

__global__ __launch_bounds__(256) void k_scan3(int* __restrict__ offs,
                                               const int* __restrict__ bsum,
                                               int N, int E) {
    int i = blockIdx.x * 256 + threadIdx.x;
    if (i < N) offs[i] = offs[i] + bsum[i >> 10];
    if (i == 0) offs[N] = E;
}

// ---------- CSR fill, atomic-free, 2D grid: x = edge chunk, y = node window ----------
__global__ __launch_bounds__(256) void k_fill3(const int* __restrict__ row,
                                               const int* __restrict__ col,
                                               const int* __restrict__ offs,
                                               const unsigned int* __restrict__ hCol,
                                               int* __restrict__ srcSorted,
                                               int E, int N, int W, int chunk) {
    __shared__ int base[NWIN];
    int t = threadIdx.x, b = blockIdx.x;
    int n0 = blockIdx.y * NWIN;
    int nCnt = min(NWIN, N - n0);
    int e0 = b * chunk, e1 = min(E, e0 + chunk);
    for (int wl = t; wl * 2 < nCnt; wl += 256) {
        unsigned int pref = hCol[(size_t)b * W + (n0 >> 1) + wl];
        int nn = n0 + wl * 2;
        base[wl * 2] = offs[nn] + (int)(pref & 0xFFFFu);
        if (wl * 2 + 1 < nCnt)
            base[wl * 2 + 1] = offs[nn + 1] + (int)(pref >> 16);
    }
    __syncthreads();
    for (int e = e0 + t; e < e1; e += 256) {
        int c = col[e] - n0;
        if ((unsigned)c < (unsigned)nCnt) {
            int pos = atomicAdd(&base[c], 1);
            srcSorted[pos] = row[e];
        }
    }
}

// ---------- conv1 gather: fp32 x in, split-bf16 agg1 out (d=64, 16 lanes/node) ----------
__global__ __launch_bounds__(256) void k_gather1(const float* __restrict__ s,
                                                 const int* __restrict__ offs,
                                                 const int* __restrict__ srcs,
                                                 const float* __restrict__ dis,
                                                 unsigned short* __restrict__ aggHi,
                                                 unsigned short* __restrict__ aggLo,
                                                 int N) {
    int tid = blockIdx.x * 256 + threadIdx.x;
    int node = tid >> 4;
    if (node >= N) return;
    int c4 = (tid & 15) * 4;
    int e = offs[node], eEnd = offs[node + 1];
    float dn = dis[node];
    float4 acc = *(const float4*)(s + (size_t)node * 64 + c4);
    acc.x *= dn; acc.y *= dn; acc.z *= dn; acc.w *= dn;
    int srcNext = (e < eEnd) ? srcs[e] : 0;
    float dNext = dis[srcNext];
    while (e < eEnd) {
        int src = srcNext;
        float dsrc = dNext;
        e++;
        srcNext = (e < eEnd) ? srcs[e] : 0;
        dNext = dis[srcNext];
        float4 v = *(const float4*)(s + (size_t)src * 64 + c4);
        acc.x += v.x * dsrc; acc.y += v.y * dsrc;
        acc.z += v.z * dsrc; acc.w += v.w * dsrc;
    }
    acc.x *= dn; acc.y *= dn; acc.z *= dn; acc.w *= dn;
    store_split4(acc, aggHi + (size_t)node * 64 + c4, aggLo + (size_t)node * 64 + c4);
}

// ---------- conv2 gather: bf16 h1 in, bf16 agg2 out (d=128, 16 lanes/node) ----------
__global__ __launch_bounds__(256) void k_gather2(const unsigned short* __restrict__ s,
                                                 const int* __restrict__ offs,
                                                 const int* __restrict__ srcs,
                                                 const float* __restrict__ dis,
                                                 unsigned short* __restrict__ agg,
                                                 int N) {
    int tid = blockIdx.x * 256 + threadIdx.x;
    int node = tid >> 4;
    if (node >= N) return;
    int c8 = (tid & 15) * 8;  // bf16 element offset; 16 B per thread
    int e = offs[node], eEnd = offs[node + 1];
    float dn = dis[node];
    uint4 w = *(const uint4*)(s + (size_t)node * 128 + c8);
    float a0 = bf2f(w.x & 0xFFFF), a1 = bf2f(w.x >> 16);
    float a2 = bf2f(w.y & 0xFFFF), a3 = bf2f(w.y >> 16);
    float a4 = bf2f(w.z & 0xFFFF), a5 = bf2f(w.z >> 16);
    float a6 = bf2f(w.w & 0xFFFF), a7 = bf2f(w.w >> 16);
    int srcNext = (e < eEnd) ? srcs[e] : 0;
    while (e < eEnd) {
        int src = srcNext;
        e++;
        srcNext = (e < eEnd) ? srcs[e] : 0;
        uint4 v = *(const uint4*)(s + (size_t)src * 128 + c8);
        a0 += bf2f(v.x & 0xFFFF); a1 += bf2f(v.x >> 16);
        a2 += bf2f(v.y & 0xFFFF); a3 += bf2f(v.y >> 16);
        a4 += bf2f(v.z & 0xFFFF); a5 += bf2f(v.z >> 16);
        a6 += bf2f(v.w & 0xFFFF); a7 += bf2f(v.w >> 16);
    }
    uint4 o;
    o.x = f2bf(a0 * dn) | (f2bf(a1 * dn) << 16);
    o.y = f2bf(a2 * dn) | (f2bf(a3 * dn) << 16);
    o.z = f2bf(a4 * dn) | (f2bf(a5 * dn) << 16);
    o.w = f2bf(a6 * dn) | (f2bf(a7 * dn) << 16);
    *(uint4*)(agg + (size_t)node * 128 + c8) = o;
}

// ---------- fold + pack weights (split bf16, MFMA B-frag layout) ----------
__global__ __launch_bounds__(256) void k_fold(const float* __restrict__ W1,
                                              const float* __restrict__ W2,
                                              const float* __restrict__ Wc1,
                                              const float* __restrict__ b2,
                                              const float* __restrict__ bc1,
                                              unsigned short* __restrict__ UVhi,
                                              unsigned short* __restrict__ UVlo,
                                              unsigned short* __restrict__ W1hi,
                                              unsigned short* __restrict__ W1lo,
                                              float* __restrict__ buv) {
    __shared__ float w2row[128];
    int t = threadIdx.x, b = blockIdx.x;
    if (b < 128) {
        int k = b;
        int j = t & 127, half = t >> 7;
        int n = half * 128 + j;
        const float* wc = Wc1 + (size_t)half * 128 * 128 + j;
        if (t < 128) w2row[t] = W2[k * 128 + t];
        __syncthreads();
        float acc = 0.f;
#pragma unroll 8
        for (int m = 0; m < 128; m++) acc += w2row[m] * wc[(size_t)m * 128];
        int kstep = k >> 5, kl = k & 31, quad = kl >> 3, j8 = kl & 7;
        int nb = n >> 4, l = quad * 16 + (n & 15);
        int pidx = ((kstep * 16 + nb) * 64 + l) * 8 + j8;
        unsigned int h = f2bf(acc);
        UVhi[pidx] = (unsigned short)h;
        UVlo[pidx] = (unsigned short)f2bf(acc - bf2f(h));
    } else if (b == 128) {
        int j = t & 127, half = t >> 7;
        const float* wc = Wc1 + (size_t)half * 128 * 128 + j;
        float acc = half ? 0.f : bc1[j];
#pragma unroll 8
        for (int m = 0; m < 128; m++) acc += b2[m] * wc[(size_t)m * 128];
        buv[half * 128 + j] = acc;
    } else {
        int idx = (b - 129) * 256 + t;  // < 8192
        int k = idx >> 7, n = idx & 127;
        float v = W1[k * 128 + n];
        int kstep = k >> 5, kl = k & 31, quad = kl >> 3, j8 = kl & 7;
        int nb = n >> 4, l = quad * 16 + (n & 15);
        int pidx = ((kstep * 8 + nb) * 64 + l) * 8 + j8;
        unsigned int h = f2bf(v);
        W1hi[pidx] = (unsigned short)h;
        W1lo[pidx] = (unsigned short)f2bf(v - bf2f(h));
    }
}

// ---------- MFMA GEMM 1: h1b = bf16(relu(agg1 @ W1 + b1) * dis) ----------
// 64 rows/block, B register-resident across 4 row groups.
__global__ __launch_bounds__(256) void k_mfma1(const unsigned short* __restrict__ Ahi,
                                               const unsigned short* __restrict__ Alo,
                                               const unsigned short* __restrict__ Bhi,
                                               const unsigned short* __restrict__ Blo,
                                               const float* __restrict__ b1,
                                               const float* __restrict__ dis,
                                               unsigned short* __restrict__ h1b, int N) {
    int lane = threadIdx.x & 63, wave = threadIdx.x >> 6;
    int quad = lane >> 4;
    short8 bh[2][2], bl[2][2];
#pragma unroll
    for (int ks = 0; ks < 2; ks++)
#pragma unroll
        for (int nt = 0; nt < 2; nt++) {
            int nb = wave * 2 + nt;
            bh[ks][nt] = *(const short8*)(Bhi + ((ks * 8 + nb) * 64 + lane) * 8);
            bl[ks][nt] = *(const short8*)(Blo + ((ks * 8 + nb) * 64 + lane) * 8);
        }
#pragma unroll
    for (int g = 0; g < 4; g++) {
        int mbase = blockIdx.x * 64 + g * 16;
        int ma = mbase + (lane & 15); if (ma >= N) ma = N - 1;
        floatx4 acc[2] = {};
#pragma unroll
        for (int ks = 0; ks < 2; ks++) {
            short8 ahi = *(const short8*)(Ahi + (size_t)ma * 64 + ks * 32 + quad * 8);
            short8 alo = *(const short8*)(Alo + (size_t)ma * 64 + ks * 32 + quad * 8);
#pragma unroll
            for (int nt = 0; nt < 2; nt++) {
                acc[nt] = __builtin_amdgcn_mfma_f32_16x16x32_bf16(ahi, bh[ks][nt], acc[nt], 0, 0, 0);
                acc[nt] = __builtin_amdgcn_mfma_f32_16x16x32_bf16(ahi, bl[ks][nt], acc[nt], 0, 0, 0);
                acc[nt] = __builtin_amdgcn_mfma_f32_16x16x32_bf16(alo, bh[ks][nt], acc[nt], 0, 0, 0);
            }
        }
        int md = mbase + quad * 4;
#pragma unroll
        for (int nt = 0; nt < 2; nt++) {
            int n0 = (wave * 2 + nt) * 16 + (lane & 15);
            float bias = b1[n0];
#pragma unroll
            for (int r = 0; r < 4; r++) {
                int node = md + r;
                if (node < N)
                    h1b[(size_t)node * 128 + n0] =
                        (unsigned short)f2bf(fmaxf(acc[nt][r] + bias, 0.f) * dis[node]);
            }
        }
    }
}

// ---------- MFMA GEMM UV: [U|V] = agg2b @ Wfull + buv ----------
// 64 rows/block, B register-resident (128 VGPR) across 4 row groups.
__global__ __launch_bounds__(256) void k_mfmaUV(const unsigned short* __restrict__ A,
                                                const unsigned short* __restrict__ Bhi,
                                                const unsigned short* __restrict__ Blo,
                                                const float* __restrict__ buv,
                                                float* __restrict__ U,
                                                float* __restrict__ V, int N) {
    int lane = threadIdx.x & 63, wave = threadIdx.x >> 6;
    int quad = lane >> 4;
    short8 bh[4][4], bl[4][4];
#pragma unroll
    for (int ks = 0; ks < 4; ks++)
#pragma unroll
        for (int nt = 0; nt < 4; nt++) {
            int nb = wave * 4 + nt;
            bh[ks][nt] = *(const short8*)(Bhi + ((ks * 16 + nb) * 64 + lane) * 8);
            bl[ks][nt] = *(const short8*)(Blo + ((ks * 16 + nb) * 64 + lane) * 8);
        }
#pragma unroll
    for (int g = 0; g < 4; g++) {
        int mbase = blockIdx.x * 64 + g * 16;
        int ma = mbase + (lane & 15); if (ma >= N) ma = N - 1;
        floatx4 acc[4] = {};
#pragma unroll
        for (int ks = 0; ks < 4; ks++) {
            short8 a = *(const short8*)(A + (size_t)ma * 128 + ks * 32 + quad * 8);
#pragma unroll
            for (int nt = 0; nt < 4; nt++) {
                acc[nt] = __builtin_amdgcn_mfma_f32_16x16x32_bf16(a, bh[ks][nt], acc[nt], 0, 0, 0);
                acc[nt] = __builtin_amdgcn_mfma_f32_16x16x32_bf16(a, bl[ks][nt], acc[nt], 0, 0, 0);
            }
        }
        int md = mbase + quad * 4;
#pragma unroll
        for (int nt = 0; nt < 4; nt++) {
            int n0 = wave * 64 + nt * 16 + (lane & 15);
            float bias = buv[n0];
            float* dst = (n0 < 128) ? U : V;
            int cc = n0 & 127;
#pragma unroll
            for (int r = 0; r < 4; r++) {
                int node = md + r;
                if (node < N)
                    dst[(size_t)node * 128 + cc] = acc[nt][r] + bias;
            }
        }
    }
}

// ---------- head: out[q] = relu(U[src]+V[dst]) . Wc2 + bc2 ----------
__global__ __launch_bounds__(256) void k_head(const float* __restrict__ U,
                                              const float* __restrict__ V,
                                              const int* __restrict__ srcA,
                                              const int* __restrict__ dstA,
                                              const float* __restrict__ Wc2,
                                              const float* __restrict__ bc2,
                                              float* __restrict__ out, int Q) {
    int t = threadIdx.x;
    int q = blockIdx.x * 16 + (t >> 4);
    if (q >= Q) return;
    int l = t & 15;
    int s = srcA[q], d = dstA[q];
    const float4* u = (const float4*)(U + (size_t)s * 128 + l * 8);
    const float4* v = (const float4*)(V + (size_t)d * 128 + l * 8);
    const float4* w = (const float4*)(Wc2 + l * 8);
    float4 u0 = u[0], u1 = u[1];
    float4 v0 = v[0], v1 = v[1];
    float4 w0 = w[0], w1 = w[1];
    float acc = 0.f, z;
    z = fmaxf(u0.x + v0.x, 0.f); acc += z * w0.x;
    z = fmaxf(u0.y + v0.y, 0.f); acc += z * w0.y;
    z = fmaxf(u0.z + v0.z, 0.f); acc += z * w0.z;
    z = fmaxf(u0.w + v0.w, 0.f); acc += z * w0.w;
    z = fmaxf(u1.x + v1.x, 0.f); acc += z * w1.x;
    z = fmaxf(u1.y + v1.y, 0.f); acc += z * w1.y;
    z = fmaxf(u1.z + v1.z, 0.f); acc += z * w1.z;
    z = fmaxf(u1.w + v1.w, 0.f); acc += z * w1.w;
    acc += __shfl_xor(acc, 1);
    acc += __shfl_xor(acc, 2);
    acc += __shfl_xor(acc, 4);
    acc += __shfl_xor(acc, 8);
    if (l == 0) out[q] = acc + bc2[0];
}

extern "C" void kernel_launch(void* const* d_in, const int* in_sizes, int n_in,
                              void* d_out, int out_size, void* d_ws, size_t ws_size,
                              hipStream_t stream) {
    const float* x   = (const float*)d_in[0];
    const int*   ei  = (const int*)d_in[1];
    const int*   eli = (const int*)d_in[2];
    const float* W1  = (const float*)d_in[3];
    const float* b1  = (const float*)d_in[4];
    const float* W2  = (const float*)d_in[5];
    const float* b2  = (const float*)d_in[6];
    const float* Wc1 = (const float*)d_in[7];
    const float* bc1 = (const float*)d_in[8];
    const float* Wc2 = (const float*)d_in[9];
    const float* bc2 = (const float*)d_in[10];
    float* out = (float*)d_out;
    char* wsb = (char*)d_ws;

    const int N = in_sizes[0] / 64;
    const int E = in_sizes[1] / 2;
    const int Q = in_sizes[2] / 2;
    const int W = (N + 1) / 2;
    const int chunk = (E + HB - 1) / HB;
    const int nPass = (N + NWIN - 1) / NWIN;        // fill windows (nodes)
    const int nWinH = (W + NWIN - 1) / NWIN;        // hist windows (words)

    // workspace layout (word offsets, 4B units); peak 17104128 words = 68.4 MB
    float* dis       = (float*)wsb;                                // 65536
    int*   offs      = (int*)wsb + 65536;                          // N+1
    int*   bsum      = (int*)wsb + 197120;                         // 256
    int*   cntCol    = (int*)wsb + 197376;                         // 65536
    float* buv       = (float*)wsb + 262912;                       // 256
    unsigned short* UVhi = (unsigned short*)((int*)wsb + 263168);  // 32768 us
    unsigned short* UVlo = (unsigned short*)((int*)wsb + 279552);
    unsigned short* W1hi = (unsigned short*)((int*)wsb + 295936);  // 8192 us
    unsigned short* W1lo = (unsigned short*)((int*)wsb + 300032);
    int*   srcSorted = (int*)wsb + 304128;                         // E -> 1104128
    // V spans [1104128, 7504128) and overlays dead agg1 + h1b at mfmaUV time
    float* V = (float*)wsb + 1104128;
    unsigned short* agg1hi = (unsigned short*)((int*)wsb + 1104128);  // N*64 us
    unsigned short* agg1lo = (unsigned short*)((int*)wsb + 2704128);
    unsigned short* h1b    = (unsigned short*)((int*)wsb + 4304128);  // N*128 us
    unsigned short* agg2b  = (unsigned short*)((int*)wsb + 7504128);  // N*128 us -> 10704128
    // U spans [10704128, 17104128) and overlays hist partials (dead after k_fill3)
    float* U = (float*)wsb + 10704128;
    unsigned int* hRow = (unsigned int*)wsb + 10704128;            // HB*W -> 13904128
    unsigned int* hCol = (unsigned int*)wsb + 13904128;            // HB*W -> 17104128

    const int* row  = ei;
    const int* col  = ei + E;
    const int* srcA = eli;
    const int* dstA = eli + Q;

    const int scanB = (N + 1023) / 1024;

    k_hist<<<dim3(HB, 2 * nWinH), 256, 0, stream>>>(row, col, hRow, hCol, E, W, chunk);
    k_reduce<<<(W + 255) / 256, 256, 0, stream>>>(hRow, hCol, cntCol, dis, N, W);
    k_scan1<<<scanB, 256, 0, stream>>>(cntCol, offs, bsum, N);
    k_scan2<<<1, 256, 0, stream>>>(bsum, scanB);
    k_scan3<<<(N + 255) / 256, 256, 0, stream>>>(offs, bsum, N, E);
    k_fill3<<<dim3(HB, nPass), 256, 0, stream>>>(row, col, offs, hCol, srcSorted, E, N, W, chunk);
    k_fold<<<161, 256, 0, stream>>>(W1, W2, Wc1, b2, bc1, UVhi, UVlo, W1hi, W1lo, buv);
    k_gather1<<<((size_t)N * 16 + 255) / 256, 256, 0, stream>>>(
        x, offs, srcSorted, dis, agg1hi, agg1lo, N);
    k_mfma1<<<(N + 63) / 64, 256, 0, stream>>>(agg1hi, agg1lo, W1hi, W1lo, b1, dis, h1b, N);
    k_gather2<<<((size_t)N * 16 + 255) / 256, 256, 0, stream>>>(
        h1b, offs, srcSorted, dis, agg2b, N);
    k_mfmaUV<<<(N + 63) / 64, 256, 0, stream>>>(agg2b, UVhi, UVlo, buv, U, V, N);
    k_head<<<(Q + 15) / 16, 256, 0, stream>>>(U, V, srcA, dstA, Wc2, bc2, out, Q);
}

// Round 10
// 280.803 us; speedup vs baseline: 1.4026x; 1.0904x over previous
//
#include <hip/hip_runtime.h>

// N=50000, E=800000, Q=200000, d_in=64, h=128
// All random-access feature arrays in bf16 (xb, h1b, agg2b, Ub, Vb);
// split-bf16 MFMA GEMMs (weights split for accuracy); atomic-free CSR build.

#define HB 128   // histogram / fill chunks
#define NWIN 16384  // node-window size (64KB LDS)

typedef __attribute__((ext_vector_type(8))) short short8;
typedef __attribute__((ext_vector_type(4))) float floatx4;

static __device__ __forceinline__ unsigned int f2bf(float v) {
    union { float f; unsigned int u; } c; c.f = v;
    unsigned int lsb = (c.u >> 16) & 1u;
    c.u += 0x7FFFu + lsb;                 // round-to-nearest-even
    return c.u >> 16;
}
static __device__ __forceinline__ float bf2f(unsigned int h) {
    union { float f; unsigned int u; } c; c.u = h << 16;
    return c.f;
}
static __device__ __forceinline__ void store_split4(float4 v,
                                                    unsigned short* hi,
                                                    unsigned short* lo) {
    unsigned int h0 = f2bf(v.x), h1 = f2bf(v.y), h2 = f2bf(v.z), h3 = f2bf(v.w);
    uint2 hw; hw.x = h0 | (h1 << 16); hw.y = h2 | (h3 << 16);
    unsigned int l0 = f2bf(v.x - bf2f(h0)), l1 = f2bf(v.y - bf2f(h1));
    unsigned int l2 = f2bf(v.z - bf2f(h2)), l3 = f2bf(v.w - bf2f(h3));
    uint2 lw; lw.x = l0 | (l1 << 16); lw.y = l2 | (l3 << 16);
    *(uint2*)hi = hw;
    *(uint2*)lo = lw;
}

// ---------- degree histogram: 2D grid (edge-chunk, array x window) ----------
__global__ __launch_bounds__(256) void k_hist(const int* __restrict__ row,
                                              const int* __restrict__ col,
                                              unsigned int* __restrict__ hRow,
                                              unsigned int* __restrict__ hCol,
                                              int E, int W, int chunk) {
    __shared__ unsigned int lds[NWIN];
    int t = threadIdx.x, b = blockIdx.x;
    int p = blockIdx.y >> 1;        // 0 = row array, 1 = col array
    int win = blockIdx.y & 1;       // word-window index
    int base = win * NWIN;
    int wcap = min(W - base, NWIN);
    if (wcap <= 0) return;
    const int* idxArr = p ? col : row;
    unsigned int* outArr = p ? hCol : hRow;
    int e0 = b * chunk, e1 = min(E, e0 + chunk);
    for (int i = t; i < wcap; i += 256) lds[i] = 0;
    __syncthreads();
    for (int e = e0 + t; e < e1; e += 256) {
        int idx = idxArr[e];
        int w = (idx >> 1) - base;
        if ((unsigned)w < (unsigned)wcap)
            atomicAdd(&lds[w], 1u << ((idx & 1) * 16));
    }
    __syncthreads();
    for (int i = t; i < wcap; i += 256)
        outArr[(size_t)b * W + base + i] = lds[i];
}

// Sum 16-bit lanes across HB partials; emit cntCol + dis, and REPLACE hCol
// partials with the exclusive prefix over blocks (packed 16-bit) for k_fill3.
__global__ __launch_bounds__(256) void k_reduce(const unsigned int* __restrict__ hRow,
                                                unsigned int* __restrict__ hCol,
                                                int* __restrict__ cntCol,
                                                float* __restrict__ dis,
                                                int N, int W) {
    int w = blockIdx.x * 256 + threadIdx.x;
    if (w >= W) return;
    unsigned int r0 = 0, r1 = 0, c0 = 0, c1 = 0;
#pragma unroll 8
    for (int b = 0; b < HB; b++) {
        size_t idx = (size_t)b * W + w;
        unsigned int hr = hRow[idx];
        unsigned int hc = hCol[idx];
        hCol[idx] = c0 | (c1 << 16);   // exclusive prefix over blocks
        r0 += hr & 0xFFFFu; r1 += hr >> 16;
        c0 += hc & 0xFFFFu; c1 += hc >> 16;
    }
    int n0 = 2 * w, n1 = 2 * w + 1;
    cntCol[n0] = (int)c0;
    dis[n0] = 1.0f / sqrtf((float)(r0 + 1));
    if (n1 < N) {
        cntCol[n1] = (int)c1;
        dis[n1] = 1.0f / sqrtf((float)(r1 + 1));
    }
}

// ---------- scan ----------
__global__ __launch_bounds__(256) void k_scan1(const int* __restrict__ cnt,
                                               int* __restrict__ offs,
                                               int* __restrict__ bsum, int N) {
    __shared__ int ts[256];
    int t = threadIdx.x;
    int base = blockIdx.x * 1024 + t * 4;
    int v0 = (base + 0 < N) ? cnt[base + 0] : 0;
    int v1 = (base + 1 < N) ? cnt[base + 1] : 0;
    int v2 = (base + 2 < N) ? cnt[base + 2] : 0;
    int v3 = (base + 3 < N) ? cnt[base + 3] : 0;
    int sum = v0 + v1 + v2 + v3;
    ts[t] = sum;
    __syncthreads();
    for (int off = 1; off < 256; off <<= 1) {
        int x = (t >= off) ? ts[t - off] : 0;
        __syncthreads();
        ts[t] += x;
        __syncthreads();
    }
    int e = ts[t] - sum;
    if (base + 0 < N) offs[base + 0] = e;
    if (base + 1 < N) offs[base + 1] = e + v0;
    if (base + 2 < N) offs[base + 2] = e + v0 + v1;
    if (base + 3 < N) offs[base + 3] = e + v0 + v1 + v2;
    if (t == 255) bsum[blockIdx.x] = ts[255];
}

__global__ __launch_bounds__(256) void k_scan2(int* __restrict__ bsum, int B) {
    __shared__ int ts[256];
    int t = threadIdx.x;
    int v = (t < B) ? bsum[t] : 0;
    ts[t] = v;
    __syncthreads();
    for (int off = 1; off < 256; off <<= 1) {
        int x = (t >= off) ? ts[t - off] : 0;
        __syncthreads();
        ts[t] += x;
        __syncthreads();
    }
    if (t < B) bsum[t] = ts[t] - v;
}

__global__ __launch_bounds__(256) void k_scan3(int* __restrict__ offs,
                                               const int* __restrict__ bsum,
                                               int N, int E) {
    int i = blockIdx.x * 256 + threadIdx.x;
    if (i < N) offs[i] = offs[i] + bsum[i >> 10];
    if (i == 0) offs[N] = E;
}

// ---------- CSR fill, atomic-free, 2D grid: x = edge chunk, y = node window ----------
__global__ __launch_bounds__(256) void k_fill3(const int* __restrict__ row,
                                               const int* __restrict__ col,
                                               const int* __restrict__ offs,
                                               const unsigned int* __restrict__ hCol,
                                               int* __restrict__ srcSorted,
                                               int E, int N, int W, int chunk) {
    __shared__ int base[NWIN];
    int t = threadIdx.x, b = blockIdx.x;
    int n0 = blockIdx.y * NWIN;
    int nCnt = min(NWIN, N - n0);
    int e0 = b * chunk, e1 = min(E, e0 + chunk);
    for (int wl = t; wl * 2 < nCnt; wl += 256) {
        unsigned int pref = hCol[(size_t)b * W + (n0 >> 1) + wl];
        int nn = n0 + wl * 2;
        base[wl * 2] = offs[nn] + (int)(pref & 0xFFFFu);
        if (wl * 2 + 1 < nCnt)
            base[wl * 2 + 1] = offs[nn + 1] + (int)(pref >> 16);
    }
    __syncthreads();
    for (int e = e0 + t; e < e1; e += 256) {
        int c = col[e] - n0;
        if ((unsigned)c < (unsigned)nCnt) {
            int pos = atomicAdd(&base[c], 1);
            srcSorted[pos] = row[e];
        }
    }
}

// ---------- x -> bf16 conversion (coalesced) ----------
__global__ __launch_bounds__(256) void k_xb(const float* __restrict__ x,
                                            unsigned int* __restrict__ xb, int nWords) {
    int i = blockIdx.x * 256 + threadIdx.x;
    if (i < nWords) {
        float2 v = ((const float2*)x)[i];
        xb[i] = f2bf(v.x) | (f2bf(v.y) << 16);
    }
}

// ---------- conv1 gather: bf16 xb in, split-bf16 agg1 out (d=64, 16 lanes/node) ----------
__global__ __launch_bounds__(256) void k_gather1(const unsigned short* __restrict__ s,
                                                 const int* __restrict__ offs,
                                                 const int* __restrict__ srcs,
                                                 const float* __restrict__ dis,
                                                 unsigned short* __restrict__ aggHi,
                                                 unsigned short* __restrict__ aggLo,
                                                 int N) {
    int tid = blockIdx.x * 256 + threadIdx.x;
    int node = tid >> 4;
    if (node >= N) return;
    int c4 = (tid & 15) * 4;  // 4 bf16 = 8 B per lane
    int e = offs[node], eEnd = offs[node + 1];
    float dn = dis[node];
    uint2 w = *(const uint2*)(s + (size_t)node * 64 + c4);
    float4 acc;
    acc.x = bf2f(w.x & 0xFFFF) * dn; acc.y = bf2f(w.x >> 16) * dn;
    acc.z = bf2f(w.y & 0xFFFF) * dn; acc.w = bf2f(w.y >> 16) * dn;
    int srcNext = (e < eEnd) ? srcs[e] : 0;
    float dNext = dis[srcNext];
    while (e < eEnd) {
        int src = srcNext;
        float dsrc = dNext;
        e++;
        srcNext = (e < eEnd) ? srcs[e] : 0;
        dNext = dis[srcNext];
        uint2 v = *(const uint2*)(s + (size_t)src * 64 + c4);
        acc.x += bf2f(v.x & 0xFFFF) * dsrc; acc.y += bf2f(v.x >> 16) * dsrc;
        acc.z += bf2f(v.y & 0xFFFF) * dsrc; acc.w += bf2f(v.y >> 16) * dsrc;
    }
    acc.x *= dn; acc.y *= dn; acc.z *= dn; acc.w *= dn;
    store_split4(acc, aggHi + (size_t)node * 64 + c4, aggLo + (size_t)node * 64 + c4);
}

// ---------- conv2 gather: bf16 h1 in, bf16 agg2 out (d=128, 16 lanes/node) ----------
__global__ __launch_bounds__(256) void k_gather2(const unsigned short* __restrict__ s,
                                                 const int* __restrict__ offs,
                                                 const int* __restrict__ srcs,
                                                 const float* __restrict__ dis,
                                                 unsigned short* __restrict__ agg,
                                                 int N) {
    int tid = blockIdx.x * 256 + threadIdx.x;
    int node = tid >> 4;
    if (node >= N) return;
    int c8 = (tid & 15) * 8;  // 8 bf16 = 16 B per lane
    int e = offs[node], eEnd = offs[node + 1];
    float dn = dis[node];
    uint4 w = *(const uint4*)(s + (size_t)node * 128 + c8);
    float a0 = bf2f(w.x & 0xFFFF), a1 = bf2f(w.x >> 16);
    float a2 = bf2f(w.y & 0xFFFF), a3 = bf2f(w.y >> 16);
    float a4 = bf2f(w.z & 0xFFFF), a5 = bf2f(w.z >> 16);
    float a6 = bf2f(w.w & 0xFFFF), a7 = bf2f(w.w >> 16);
    int srcNext = (e < eEnd) ? srcs[e] : 0;
    while (e < eEnd) {
        int src = srcNext;
        e++;
        srcNext = (e < eEnd) ? srcs[e] : 0;
        uint4 v = *(const uint4*)(s + (size_t)src * 128 + c8);
        a0 += bf2f(v.x & 0xFFFF); a1 += bf2f(v.x >> 16);
        a2 += bf2f(v.y & 0xFFFF); a3 += bf2f(v.y >> 16);
        a4 += bf2f(v.z & 0xFFFF); a5 += bf2f(v.z >> 16);
        a6 += bf2f(v.w & 0xFFFF); a7 += bf2f(v.w >> 16);
    }
    uint4 o;
    o.x = f2bf(a0 * dn) | (f2bf(a1 * dn) << 16);
    o.y = f2bf(a2 * dn) | (f2bf(a3 * dn) << 16);
    o.z = f2bf(a4 * dn) | (f2bf(a5 * dn) << 16);
    o.w = f2bf(a6 * dn) | (f2bf(a7 * dn) << 16);
    *(uint4*)(agg + (size_t)node * 128 + c8) = o;
}

// ---------- fold + pack weights (split bf16, MFMA B-frag layout) ----------
__global__ __launch_bounds__(256) void k_fold(const float* __restrict__ W1,
                                              const float* __restrict__ W2,
                                              const float* __restrict__ Wc1,
                                              const float* __restrict__ b2,
                                              const float* __restrict__ bc1,
                                              unsigned short* __restrict__ UVhi,
                                              unsigned short* __restrict__ UVlo,
                                              unsigned short* __restrict__ W1hi,
                                              unsigned short* __restrict__ W1lo,
                                              float* __restrict__ buv) {
    __shared__ float w2row[128];
    int t = threadIdx.x, b = blockIdx.x;
    if (b < 128) {
        int k = b;
        int j = t & 127, half = t >> 7;
        int n = half * 128 + j;
        const float* wc = Wc1 + (size_t)half * 128 * 128 + j;
        if (t < 128) w2row[t] = W2[k * 128 + t];
        __syncthreads();
        float acc = 0.f;
#pragma unroll 8
        for (int m = 0; m < 128; m++) acc += w2row[m] * wc[(size_t)m * 128];
        int kstep = k >> 5, kl = k & 31, quad = kl >> 3, j8 = kl & 7;
        int nb = n >> 4, l = quad * 16 + (n & 15);
        int pidx = ((kstep * 16 + nb) * 64 + l) * 8 + j8;
        unsigned int h = f2bf(acc);
        UVhi[pidx] = (unsigned short)h;
        UVlo[pidx] = (unsigned short)f2bf(acc - bf2f(h));
    } else if (b == 128) {
        int j = t & 127, half = t >> 7;
        const float* wc = Wc1 + (size_t)half * 128 * 128 + j;
        float acc = half ? 0.f : bc1[j];
#pragma unroll 8
        for (int m = 0; m < 128; m++) acc += b2[m] * wc[(size_t)m * 128];
        buv[half * 128 + j] = acc;
    } else {
        int idx = (b - 129) * 256 + t;  // < 8192
        int k = idx >> 7, n = idx & 127;
        float v = W1[k * 128 + n];
        int kstep = k >> 5, kl = k & 31, quad = kl >> 3, j8 = kl & 7;
        int nb = n >> 4, l = quad * 16 + (n & 15);
        int pidx = ((kstep * 8 + nb) * 64 + l) * 8 + j8;
        unsigned int h = f2bf(v);
        W1hi[pidx] = (unsigned short)h;
        W1lo[pidx] = (unsigned short)f2bf(v - bf2f(h));
    }
}

// ---------- MFMA GEMM 1: h1b = bf16(relu(agg1 @ W1 + b1) * dis) ----------
// 64 rows/block, B register-resident across 4 row groups.
__global__ __launch_bounds__(256) void k_mfma1(const unsigned short* __restrict__ Ahi,
                                               const unsigned short* __restrict__ Alo,
                                               const unsigned short* __restrict__ Bhi,
                                               const unsigned short* __restrict__ Blo,
                                               const float* __restrict__ b1,
                                               const float* __restrict__ dis,
                                               unsigned short* __restrict__ h1b, int N) {
    int lane = threadIdx.x & 63, wave = threadIdx.x >> 6;
    int quad = lane >> 4;
    short8 bh[2][2], bl[2][2];
#pragma unroll
    for (int ks = 0; ks < 2; ks++)
#pragma unroll
        for (int nt = 0; nt < 2; nt++) {
            int nb = wave * 2 + nt;
            bh[ks][nt] = *(const short8*)(Bhi + ((ks * 8 + nb) * 64 + lane) * 8);
            bl[ks][nt] = *(const short8*)(Blo + ((ks * 8 + nb) * 64 + lane) * 8);
        }
#pragma unroll
    for (int g = 0; g < 4; g++) {
        int mbase = blockIdx.x * 64 + g * 16;
        int ma = mbase + (lane & 15); if (ma >= N) ma = N - 1;
        floatx4 acc[2] = {};
#pragma unroll
        for (int ks = 0; ks < 2; ks++) {
            short8 ahi = *(const short8*)(Ahi + (size_t)ma * 64 + ks * 32 + quad * 8);
            short8 alo = *(const short8*)(Alo + (size_t)ma * 64 + ks * 32 + quad * 8);
#pragma unroll
            for (int nt = 0; nt < 2; nt++) {
                acc[nt] = __builtin_amdgcn_mfma_f32_16x16x32_bf16(ahi, bh[ks][nt], acc[nt], 0, 0, 0);
                acc[nt] = __builtin_amdgcn_mfma_f32_16x16x32_bf16(ahi, bl[ks][nt], acc[nt], 0, 0, 0);
                acc[nt] = __builtin_amdgcn_mfma_f32_16x16x32_bf16(alo, bh[ks][nt], acc[nt], 0, 0, 0);
            }
        }
        int md = mbase + quad * 4;
#pragma unroll
        for (int nt = 0; nt < 2; nt++) {
            int n0 = (wave * 2 + nt) * 16 + (lane & 15);
            float bias = b1[n0];
#pragma unroll
            for (int r = 0; r < 4; r++) {
                int node = md + r;
                if (node < N)
                    h1b[(size_t)node * 128 + n0] =
                        (unsigned short)f2bf(fmaxf(acc[nt][r] + bias, 0.f) * dis[node]);
            }
        }
    }
}

// ---------- MFMA GEMM UV: [Ub|Vb] = bf16(agg2b @ Wfull + buv) ----------
// 64 rows/block, B register-resident (128 VGPR) across 4 row groups.
__global__ __launch_bounds__(256) void k_mfmaUV(const unsigned short* __restrict__ A,
                                                const unsigned short* __restrict__ Bhi,
                                                const unsigned short* __restrict__ Blo,
                                                const float* __restrict__ buv,
                                                unsigned short* __restrict__ Ub,
                                                unsigned short* __restrict__ Vb, int N) {
    int lane = threadIdx.x & 63, wave = threadIdx.x >> 6;
    int quad = lane >> 4;
    short8 bh[4][4], bl[4][4];
#pragma unroll
    for (int ks = 0; ks < 4; ks++)
#pragma unroll
        for (int nt = 0; nt < 4; nt++) {
            int nb = wave * 4 + nt;
            bh[ks][nt] = *(const short8*)(Bhi + ((ks * 16 + nb) * 64 + lane) * 8);
            bl[ks][nt] = *(const short8*)(Blo + ((ks * 16 + nb) * 64 + lane) * 8);
        }
#pragma unroll
    for (int g = 0; g < 4; g++) {
        int mbase = blockIdx.x * 64 + g * 16;
        int ma = mbase + (lane & 15); if (ma >= N) ma = N - 1;
        floatx4 acc[4] = {};
#pragma unroll
        for (int ks = 0; ks < 4; ks++) {
            short8 a = *(const short8*)(A + (size_t)ma * 128 + ks * 32 + quad * 8);
#pragma unroll
            for (int nt = 0; nt < 4; nt++) {
                acc[nt] = __builtin_amdgcn_mfma_f32_16x16x32_bf16(a, bh[ks][nt], acc[nt], 0, 0, 0);
                acc[nt] = __builtin_amdgcn_mfma_f32_16x16x32_bf16(a, bl[ks][nt], acc[nt], 0, 0, 0);
            }
        }
        int md = mbase + quad * 4;
#pragma unroll
        for (int nt = 0; nt < 4; nt++) {
            int n0 = wave * 64 + nt * 16 + (lane & 15);
            float bias = buv[n0];
            unsigned short* dst = (n0 < 128) ? Ub : Vb;
            int cc = n0 & 127;
#pragma unroll
            for (int r = 0; r < 4; r++) {
                int node = md + r;
                if (node < N)
                    dst[(size_t)node * 128 + cc] =
                        (unsigned short)f2bf(acc[nt][r] + bias);
            }
        }
    }
}

// ---------- head: out[q] = relu(Ub[src]+Vb[dst]) . Wc2 + bc2 ----------
__global__ __launch_bounds__(256) void k_head(const unsigned short* __restrict__ Ub,
                                              const unsigned short* __restrict__ Vb,
                                              const int* __restrict__ srcA,
                                              const int* __restrict__ dstA,
                                              const float* __restrict__ Wc2,
                                              const float* __restrict__ bc2,
                                              float* __restrict__ out, int Q) {
    int t = threadIdx.x;
    int q = blockIdx.x * 16 + (t >> 4);
    if (q >= Q) return;
    int l = t & 15;
    int s = srcA[q], d = dstA[q];
    uint4 u = *(const uint4*)(Ub + (size_t)s * 128 + l * 8);
    uint4 v = *(const uint4*)(Vb + (size_t)d * 128 + l * 8);
    const float4* w = (const float4*)(Wc2 + l * 8);
    float4 w0 = w[0], w1 = w[1];
    float acc = 0.f, z;
    z = fmaxf(bf2f(u.x & 0xFFFF) + bf2f(v.x & 0xFFFF), 0.f); acc += z * w0.x;
    z = fmaxf(bf2f(u.x >> 16)    + bf2f(v.x >> 16),    0.f); acc += z * w0.y;
    z = fmaxf(bf2f(u.y & 0xFFFF) + bf2f(v.y & 0xFFFF), 0.f); acc += z * w0.z;
    z = fmaxf(bf2f(u.y >> 16)    + bf2f(v.y >> 16),    0.f); acc += z * w0.w;
    z = fmaxf(bf2f(u.z & 0xFFFF) + bf2f(v.z & 0xFFFF), 0.f); acc += z * w1.x;
    z = fmaxf(bf2f(u.z >> 16)    + bf2f(v.z >> 16),    0.f); acc += z * w1.y;
    z = fmaxf(bf2f(u.w & 0xFFFF) + bf2f(v.w & 0xFFFF), 0.f); acc += z * w1.z;
    z = fmaxf(bf2f(u.w >> 16)    + bf2f(v.w >> 16),    0.f); acc += z * w1.w;
    acc += __shfl_xor(acc, 1);
    acc += __shfl_xor(acc, 2);
    acc += __shfl_xor(acc, 4);
    acc += __shfl_xor(acc, 8);
    if (l == 0) out[q] = acc + bc2[0];
}

extern "C" void kernel_launch(void* const* d_in, const int* in_sizes, int n_in,
                              void* d_out, int out_size, void* d_ws, size_t ws_size,
                              hipStream_t stream) {
    const float* x   = (const float*)d_in[0];
    const int*   ei  = (const int*)d_in[1];
    const int*   eli = (const int*)d_in[2];
    const float* W1  = (const float*)d_in[3];
    const float* b1  = (const float*)d_in[4];
    const float* W2  = (const float*)d_in[5];
    const float* b2  = (const float*)d_in[6];
    const float* Wc1 = (const float*)d_in[7];
    const float* bc1 = (const float*)d_in[8];
    const float* Wc2 = (const float*)d_in[9];
    const float* bc2 = (const float*)d_in[10];
    float* out = (float*)d_out;
    char* wsb = (char*)d_ws;

    const int N = in_sizes[0] / 64;
    const int E = in_sizes[1] / 2;
    const int Q = in_sizes[2] / 2;
    const int W = (N + 1) / 2;
    const int chunk = (E + HB - 1) / HB;
    const int nPass = (N + NWIN - 1) / NWIN;        // fill windows (nodes)
    const int nWinH = (W + NWIN - 1) / NWIN;        // hist windows (words)

    // workspace layout (word offsets, 4B units); peak 17104128 words = 68.4 MB
    float* dis       = (float*)wsb;                                // 65536
    int*   offs      = (int*)wsb + 65536;                          // N+1
    int*   bsum      = (int*)wsb + 197120;                         // 256
    int*   cntCol    = (int*)wsb + 197376;                         // 65536
    float* buv       = (float*)wsb + 262912;                       // 256
    unsigned short* UVhi = (unsigned short*)((int*)wsb + 263168);  // 32768 us
    unsigned short* UVlo = (unsigned short*)((int*)wsb + 279552);
    unsigned short* W1hi = (unsigned short*)((int*)wsb + 295936);  // 8192 us
    unsigned short* W1lo = (unsigned short*)((int*)wsb + 300032);
    int*   srcSorted = (int*)wsb + 304128;                         // E -> 1104128
    unsigned short* agg1hi = (unsigned short*)((int*)wsb + 1104128);  // N*64 us
    unsigned short* agg1lo = (unsigned short*)((int*)wsb + 2704128);  // -> 4304128
    unsigned short* h1b    = (unsigned short*)((int*)wsb + 4304128);  // N*128 us -> 7504128
    unsigned short* agg2b  = (unsigned short*)((int*)wsb + 7504128);  // N*128 us -> 10704128
    // Vb overlays dead agg1; Ub overlays dead h1b (after gather2)
    unsigned short* Vb = agg1hi;
    unsigned short* Ub = h1b;
    // hist partials (dead after fill3); xb overlays hRow (dead after reduce)
    unsigned int* hRow = (unsigned int*)wsb + 10704128;            // HB*W -> 13904128
    unsigned int* hCol = (unsigned int*)wsb + 13904128;            // HB*W -> 17104128
    unsigned int* xb   = (unsigned int*)wsb + 10704128;            // N*32 words

    const int* row  = ei;
    const int* col  = ei + E;
    const int* srcA = eli;
    const int* dstA = eli + Q;

    const int scanB = (N + 1023) / 1024;

    k_hist<<<dim3(HB, 2 * nWinH), 256, 0, stream>>>(row, col, hRow, hCol, E, W, chunk);
    k_reduce<<<(W + 255) / 256, 256, 0, stream>>>(hRow, hCol, cntCol, dis, N, W);
    k_scan1<<<scanB, 256, 0, stream>>>(cntCol, offs, bsum, N);
    k_scan2<<<1, 256, 0, stream>>>(bsum, scanB);
    k_scan3<<<(N + 255) / 256, 256, 0, stream>>>(offs, bsum, N, E);
    k_xb<<<(N * 32 + 255) / 256, 256, 0, stream>>>(x, xb, N * 32);
    k_fill3<<<dim3(HB, nPass), 256, 0, stream>>>(row, col, offs, hCol, srcSorted, E, N, W, chunk);
    k_fold<<<161, 256, 0, stream>>>(W1, W2, Wc1, b2, bc1, UVhi, UVlo, W1hi, W1lo, buv);
    k_gather1<<<((size_t)N * 16 + 255) / 256, 256, 0, stream>>>(
        (const unsigned short*)xb, offs, srcSorted, dis, agg1hi, agg1lo, N);
    k_mfma1<<<(N + 63) / 64, 256, 0, stream>>>(agg1hi, agg1lo, W1hi, W1lo, b1, dis, h1b, N);
    k_gather2<<<((size_t)N * 16 + 255) / 256, 256, 0, stream>>>(
        h1b, offs, srcSorted, dis, agg2b, N);
    k_mfmaUV<<<(N + 63) / 64, 256, 0, stream>>>(agg2b, UVhi, UVlo, buv, Ub, Vb, N);
    k_head<<<(Q + 15) / 16, 256, 0, stream>>>(Ub, Vb, srcA, dstA, Wc2, bc2, out, Q);
}

// Round 11
// 280.525 us; speedup vs baseline: 1.4040x; 1.0010x over previous
//
#include <hip/hip_runtime.h>

// N=50000, E=800000, Q=200000, d_in=64, h=128
// bf16 random-access features; split-bf16 MFMA; atomic-free CSR build.
// Fusions: hist+xb+fold in one launch; gather1+mfma1 fused via LDS (k_conv1).

#define HB 128      // histogram / fill chunks
#define NWIN 16384  // node/word window (64KB LDS)

typedef __attribute__((ext_vector_type(8))) short short8;
typedef __attribute__((ext_vector_type(4))) float floatx4;

static __device__ __forceinline__ unsigned int f2bf(float v) {
    union { float f; unsigned int u; } c; c.f = v;
    unsigned int lsb = (c.u >> 16) & 1u;
    c.u += 0x7FFFu + lsb;                 // round-to-nearest-even
    return c.u >> 16;
}
static __device__ __forceinline__ float bf2f(unsigned int h) {
    union { float f; unsigned int u; } c; c.u = h << 16;
    return c.f;
}

// ---------- fused prologue: histogram + x->bf16 + weight fold/pack ----------
// blocks [0, nHist): histogram   (nHist = HB * 2 * nWinH, nWinH = 2)
// blocks [nHist, nHist+nXb): x -> bf16
// blocks [nHist+nXb, +161): fold W2@Wc1 + pack W1 (split bf16, B-frag layout)
__global__ __launch_bounds__(256) void k_pre(const int* __restrict__ row,
                                             const int* __restrict__ col,
                                             unsigned int* __restrict__ hRow,
                                             unsigned int* __restrict__ hCol,
                                             const float* __restrict__ x,
                                             unsigned int* __restrict__ xb,
                                             const float* __restrict__ W1,
                                             const float* __restrict__ W2,
                                             const float* __restrict__ Wc1,
                                             const float* __restrict__ b2,
                                             const float* __restrict__ bc1,
                                             unsigned short* __restrict__ UVhi,
                                             unsigned short* __restrict__ UVlo,
                                             unsigned short* __restrict__ W1hi,
                                             unsigned short* __restrict__ W1lo,
                                             float* __restrict__ buv,
                                             int E, int N, int W, int chunk,
                                             int nHist, int nXb) {
    __shared__ unsigned int lds[NWIN];
    int t = threadIdx.x, b = blockIdx.x;
    if (b < nHist) {
        int hb = b % HB;
        int yb = b / HB;
        int p = yb >> 1, win = yb & 1;
        int base = win * NWIN;
        int wcap = min(W - base, NWIN);
        if (wcap <= 0) return;
        const int* idxArr = p ? col : row;
        unsigned int* outArr = p ? hCol : hRow;
        int e0 = hb * chunk, e1 = min(E, e0 + chunk);
        for (int i = t; i < wcap; i += 256) lds[i] = 0;
        __syncthreads();
        for (int e = e0 + t; e < e1; e += 256) {
            int idx = idxArr[e];
            int w = (idx >> 1) - base;
            if ((unsigned)w < (unsigned)wcap)
                atomicAdd(&lds[w], 1u << ((idx & 1) * 16));
        }
        __syncthreads();
        for (int i = t; i < wcap; i += 256)
            outArr[(size_t)hb * W + base + i] = lds[i];
    } else if (b < nHist + nXb) {
        int i = (b - nHist) * 256 + t;
        if (i < N * 32) {
            float2 v = ((const float2*)x)[i];
            xb[i] = f2bf(v.x) | (f2bf(v.y) << 16);
        }
    } else {
        int bf = b - nHist - nXb;
        float* w2row = (float*)lds;
        if (bf < 128) {
            int k = bf;
            int j = t & 127, half = t >> 7;
            int n = half * 128 + j;
            const float* wc = Wc1 + (size_t)half * 128 * 128 + j;
            if (t < 128) w2row[t] = W2[k * 128 + t];
            __syncthreads();
            float acc = 0.f;
#pragma unroll 8
            for (int m = 0; m < 128; m++) acc += w2row[m] * wc[(size_t)m * 128];
            int kstep = k >> 5, kl = k & 31, quad = kl >> 3, j8 = kl & 7;
            int nb = n >> 4, l = quad * 16 + (n & 15);
            int pidx = ((kstep * 16 + nb) * 64 + l) * 8 + j8;
            unsigned int h = f2bf(acc);
            UVhi[pidx] = (unsigned short)h;
            UVlo[pidx] = (unsigned short)f2bf(acc - bf2f(h));
        } else if (bf == 128) {
            int j = t & 127, half = t >> 7;
            const float* wc = Wc1 + (size_t)half * 128 * 128 + j;
            float acc = half ? 0.f : bc1[j];
#pragma unroll 8
            for (int m = 0; m < 128; m++) acc += b2[m] * wc[(size_t)m * 128];
            buv[half * 128 + j] = acc;
        } else {
            int idx = (bf - 129) * 256 + t;  // < 8192
            int k = idx >> 7, n = idx & 127;
            float v = W1[k * 128 + n];
            int kstep = k >> 5, kl = k & 31, quad = kl >> 3, j8 = kl & 7;
            int nb = n >> 4, l = quad * 16 + (n & 15);
            int pidx = ((kstep * 8 + nb) * 64 + l) * 8 + j8;
            unsigned int h = f2bf(v);
            W1hi[pidx] = (unsigned short)h;
            W1lo[pidx] = (unsigned short)f2bf(v - bf2f(h));
        }
    }
}

// Sum 16-bit lanes across HB partials; emit cntCol + dis; REPLACE hCol with
// the exclusive prefix over blocks (packed 16-bit) for k_fill3.
__global__ __launch_bounds__(256) void k_reduce(const unsigned int* __restrict__ hRow,
                                                unsigned int* __restrict__ hCol,
                                                int* __restrict__ cntCol,
                                                float* __restrict__ dis,
                                                int N, int W) {
    int w = blockIdx.x * 256 + threadIdx.x;
    if (w >= W) return;
    unsigned int r0 = 0, r1 = 0, c0 = 0, c1 = 0;
#pragma unroll 8
    for (int b = 0; b < HB; b++) {
        size_t idx = (size_t)b * W + w;
        unsigned int hr = hRow[idx];
        unsigned int hc = hCol[idx];
        hCol[idx] = c0 | (c1 << 16);
        r0 += hr & 0xFFFFu; r1 += hr >> 16;
        c0 += hc & 0xFFFFu; c1 += hc >> 16;
    }
    int n0 = 2 * w, n1 = 2 * w + 1;
    cntCol[n0] = (int)c0;
    dis[n0] = 1.0f / sqrtf((float)(r0 + 1));
    if (n1 < N) {
        cntCol[n1] = (int)c1;
        dis[n1] = 1.0f / sqrtf((float)(r1 + 1));
    }
}

// ---------- scan ----------
__global__ __launch_bounds__(256) void k_scan1(const int* __restrict__ cnt,
                                               int* __restrict__ offs,
                                               int* __restrict__ bsum, int N) {
    __shared__ int ts[256];
    int t = threadIdx.x;
    int base = blockIdx.x * 1024 + t * 4;
    int v0 = (base + 0 < N) ? cnt[base + 0] : 0;
    int v1 = (base + 1 < N) ? cnt[base + 1] : 0;
    int v2 = (base + 2 < N) ? cnt[base + 2] : 0;
    int v3 = (base + 3 < N) ? cnt[base + 3] : 0;
    int sum = v0 + v1 + v2 + v3;
    ts[t] = sum;
    __syncthreads();
    for (int off = 1; off < 256; off <<= 1) {
        int x = (t >= off) ? ts[t - off] : 0;
        __syncthreads();
        ts[t] += x;
        __syncthreads();
    }
    int e = ts[t] - sum;
    if (base + 0 < N) offs[base + 0] = e;
    if (base + 1 < N) offs[base + 1] = e + v0;
    if (base + 2 < N) offs[base + 2] = e + v0 + v1;
    if (base + 3 < N) offs[base + 3] = e + v0 + v1 + v2;
    if (t == 255) bsum[blockIdx.x] = ts[255];
}

__global__ __launch_bounds__(256) void k_scan2(int* __restrict__ bsum, int B) {
    __shared__ int ts[256];
    int t = threadIdx.x;
    int v = (t < B) ? bsum[t] : 0;
    ts[t] = v;
    __syncthreads();
    for (int off = 1; off < 256; off <<= 1) {
        int x = (t >= off) ? ts[t - off] : 0;
        __syncthreads();
        ts[t] += x;
        __syncthreads();
    }
    if (t < B) bsum[t] = ts[t] - v;
}

__global__ __launch_bounds__(256) void k_scan3(int* __restrict__ offs,
                                               const int* __restrict__ bsum,
                                               int N, int E) {
    int i = blockIdx.x * 256 + threadIdx.x;
    if (i < N) offs[i] = offs[i] + bsum[i >> 10];
    if (i == 0) offs[N] = E;
}

// ---------- CSR fill, atomic-free, 2D grid ----------
__global__ __launch_bounds__(256) void k_fill3(const int* __restrict__ row,
                                               const int* __restrict__ col,
                                               const int* __restrict__ offs,
                                               const unsigned int* __restrict__ hCol,
                                               int* __restrict__ srcSorted,
                                               int E, int N, int W, int chunk) {
    __shared__ int base[NWIN];
    int t = threadIdx.x, b = blockIdx.x;
    int n0 = blockIdx.y * NWIN;
    int nCnt = min(NWIN, N - n0);
    int e0 = b * chunk, e1 = min(E, e0 + chunk);
    for (int wl = t; wl * 2 < nCnt; wl += 256) {
        unsigned int pref = hCol[(size_t)b * W + (n0 >> 1) + wl];
        int nn = n0 + wl * 2;
        base[wl * 2] = offs[nn] + (int)(pref & 0xFFFFu);
        if (wl * 2 + 1 < nCnt)
            base[wl * 2 + 1] = offs[nn + 1] + (int)(pref >> 16);
    }
    __syncthreads();
    for (int e = e0 + t; e < e1; e += 256) {
        int c = col[e] - n0;
        if ((unsigned)c < (unsigned)nCnt) {
            int pos = atomicAdd(&base[c], 1);
            srcSorted[pos] = row[e];
        }
    }
}

// ---------- fused conv1: gather(d=64, bf16 in) -> LDS split-bf16 -> MFMA -> h1b ----------
// 64 nodes/block. LDS rows padded to 72 bf16 (16B-aligned, conflict-free b128).
__global__ __launch_bounds__(256) void k_conv1(const unsigned short* __restrict__ s,
                                               const int* __restrict__ offs,
                                               const int* __restrict__ srcs,
                                               const float* __restrict__ dis,
                                               const unsigned short* __restrict__ Bhi,
                                               const unsigned short* __restrict__ Blo,
                                               const float* __restrict__ b1,
                                               unsigned short* __restrict__ h1b, int N) {
    __shared__ unsigned short Ahi[64][72];
    __shared__ unsigned short Alo[64][72];
    int t = threadIdx.x;
    int lane = t & 63, wave = t >> 6;
    int quad = lane >> 4;
    // B register-resident (independent of gather)
    short8 bh[2][2], bl[2][2];
#pragma unroll
    for (int ks = 0; ks < 2; ks++)
#pragma unroll
        for (int nt = 0; nt < 2; nt++) {
            int nb = wave * 2 + nt;
            bh[ks][nt] = *(const short8*)(Bhi + ((ks * 8 + nb) * 64 + lane) * 8);
            bl[ks][nt] = *(const short8*)(Blo + ((ks * 8 + nb) * 64 + lane) * 8);
        }
    // gather phase: 4 passes x 16 nodes (16 lanes/node)
#pragma unroll
    for (int pass = 0; pass < 4; pass++) {
        int nl = pass * 16 + (t >> 4);
        int node = blockIdx.x * 64 + nl;
        if (node < N) {
            int c4 = (t & 15) * 4;
            int e = offs[node], eEnd = offs[node + 1];
            float dn = dis[node];
            uint2 w = *(const uint2*)(s + (size_t)node * 64 + c4);
            float4 acc;
            acc.x = bf2f(w.x & 0xFFFF) * dn; acc.y = bf2f(w.x >> 16) * dn;
            acc.z = bf2f(w.y & 0xFFFF) * dn; acc.w = bf2f(w.y >> 16) * dn;
            while (e + 1 < eEnd) {
                int sA = srcs[e], sB = srcs[e + 1];
                float dA = dis[sA], dB = dis[sB];
                uint2 vA = *(const uint2*)(s + (size_t)sA * 64 + c4);
                uint2 vB = *(const uint2*)(s + (size_t)sB * 64 + c4);
                acc.x += bf2f(vA.x & 0xFFFF) * dA + bf2f(vB.x & 0xFFFF) * dB;
                acc.y += bf2f(vA.x >> 16) * dA + bf2f(vB.x >> 16) * dB;
                acc.z += bf2f(vA.y & 0xFFFF) * dA + bf2f(vB.y & 0xFFFF) * dB;
                acc.w += bf2f(vA.y >> 16) * dA + bf2f(vB.y >> 16) * dB;
                e += 2;
            }
            if (e < eEnd) {
                int sA = srcs[e];
                float dA = dis[sA];
                uint2 vA = *(const uint2*)(s + (size_t)sA * 64 + c4);
                acc.x += bf2f(vA.x & 0xFFFF) * dA; acc.y += bf2f(vA.x >> 16) * dA;
                acc.z += bf2f(vA.y & 0xFFFF) * dA; acc.w += bf2f(vA.y >> 16) * dA;
            }
            acc.x *= dn; acc.y *= dn; acc.z *= dn; acc.w *= dn;
            unsigned int h0 = f2bf(acc.x), h1 = f2bf(acc.y),
                         h2 = f2bf(acc.z), h3 = f2bf(acc.w);
            uint2 hw; hw.x = h0 | (h1 << 16); hw.y = h2 | (h3 << 16);
            uint2 lw;
            lw.x = f2bf(acc.x - bf2f(h0)) | (f2bf(acc.y - bf2f(h1)) << 16);
            lw.y = f2bf(acc.z - bf2f(h2)) | (f2bf(acc.w - bf2f(h3)) << 16);
            *(uint2*)(&Ahi[nl][c4]) = hw;
            *(uint2*)(&Alo[nl][c4]) = lw;
        }
    }
    __syncthreads();
    // MFMA phase: 4 groups of 16 rows
#pragma unroll
    for (int g = 0; g < 4; g++) {
        int ml = g * 16 + (lane & 15);
        floatx4 acc[2] = {};
#pragma unroll
        for (int ks = 0; ks < 2; ks++) {
            short8 ahi = *(const short8*)(&Ahi[ml][ks * 32 + quad * 8]);
            short8 alo = *(const short8*)(&Alo[ml][ks * 32 + quad * 8]);
#pragma unroll
            for (int nt = 0; nt < 2; nt++) {
                acc[nt] = __builtin_amdgcn_mfma_f32_16x16x32_bf16(ahi, bh[ks][nt], acc[nt], 0, 0, 0);
                acc[nt] = __builtin_amdgcn_mfma_f32_16x16x32_bf16(ahi, bl[ks][nt], acc[nt], 0, 0, 0);
                acc[nt] = __builtin_amdgcn_mfma_f32_16x16x32_bf16(alo, bh[ks][nt], acc[nt], 0, 0, 0);
            }
        }
        int md = blockIdx.x * 64 + g * 16 + quad * 4;
#pragma unroll
        for (int nt = 0; nt < 2; nt++) {
            int n0 = (wave * 2 + nt) * 16 + (lane & 15);
            float bias = b1[n0];
#pragma unroll
            for (int r = 0; r < 4; r++) {
                int node = md + r;
                if (node < N)
                    h1b[(size_t)node * 128 + n0] =
                        (unsigned short)f2bf(fmaxf(acc[nt][r] + bias, 0.f) * dis[node]);
            }
        }
    }
}

// ---------- conv2 gather: bf16 h1 in, bf16 agg2 out (d=128, 16 lanes/node) ----------
__global__ __launch_bounds__(256) void k_gather2(const unsigned short* __restrict__ s,
                                                 const int* __restrict__ offs,
                                                 const int* __restrict__ srcs,
                                                 const float* __restrict__ dis,
                                                 unsigned short* __restrict__ agg,
                                                 int N) {
    int tid = blockIdx.x * 256 + threadIdx.x;
    int node = tid >> 4;
    if (node >= N) return;
    int c8 = (tid & 15) * 8;
    int e = offs[node], eEnd = offs[node + 1];
    float dn = dis[node];
    uint4 w = *(const uint4*)(s + (size_t)node * 128 + c8);
    float a0 = bf2f(w.x & 0xFFFF), a1 = bf2f(w.x >> 16);
    float a2 = bf2f(w.y & 0xFFFF), a3 = bf2f(w.y >> 16);
    float a4 = bf2f(w.z & 0xFFFF), a5 = bf2f(w.z >> 16);
    float a6 = bf2f(w.w & 0xFFFF), a7 = bf2f(w.w >> 16);
    while (e + 1 < eEnd) {
        int sA = srcs[e], sB = srcs[e + 1];
        uint4 vA = *(const uint4*)(s + (size_t)sA * 128 + c8);
        uint4 vB = *(const uint4*)(s + (size_t)sB * 128 + c8);
        a0 += bf2f(vA.x & 0xFFFF) + bf2f(vB.x & 0xFFFF);
        a1 += bf2f(vA.x >> 16) + bf2f(vB.x >> 16);
        a2 += bf2f(vA.y & 0xFFFF) + bf2f(vB.y & 0xFFFF);
        a3 += bf2f(vA.y >> 16) + bf2f(vB.y >> 16);
        a4 += bf2f(vA.z & 0xFFFF) + bf2f(vB.z & 0xFFFF);
        a5 += bf2f(vA.z >> 16) + bf2f(vB.z >> 16);
        a6 += bf2f(vA.w & 0xFFFF) + bf2f(vB.w & 0xFFFF);
        a7 += bf2f(vA.w >> 16) + bf2f(vB.w >> 16);
        e += 2;
    }
    if (e < eEnd) {
        int sA = srcs[e];
        uint4 vA = *(const uint4*)(s + (size_t)sA * 128 + c8);
        a0 += bf2f(vA.x & 0xFFFF); a1 += bf2f(vA.x >> 16);
        a2 += bf2f(vA.y & 0xFFFF); a3 += bf2f(vA.y >> 16);
        a4 += bf2f(vA.z & 0xFFFF); a5 += bf2f(vA.z >> 16);
        a6 += bf2f(vA.w & 0xFFFF); a7 += bf2f(vA.w >> 16);
    }
    uint4 o;
    o.x = f2bf(a0 * dn) | (f2bf(a1 * dn) << 16);
    o.y = f2bf(a2 * dn) | (f2bf(a3 * dn) << 16);
    o.z = f2bf(a4 * dn) | (f2bf(a5 * dn) << 16);
    o.w = f2bf(a6 * dn) | (f2bf(a7 * dn) << 16);
    *(uint4*)(agg + (size_t)node * 128 + c8) = o;
}

// ---------- MFMA GEMM UV: [Ub|Vb] = bf16(agg2b @ Wfull + buv) ----------
__global__ __launch_bounds__(256) void k_mfmaUV(const unsigned short* __restrict__ A,
                                                const unsigned short* __restrict__ Bhi,
                                                const unsigned short* __restrict__ Blo,
                                                const float* __restrict__ buv,
                                                unsigned short* __restrict__ Ub,
                                                unsigned short* __restrict__ Vb, int N) {
    int lane = threadIdx.x & 63, wave = threadIdx.x >> 6;
    int quad = lane >> 4;
    short8 bh[4][4], bl[4][4];
#pragma unroll
    for (int ks = 0; ks < 4; ks++)
#pragma unroll
        for (int nt = 0; nt < 4; nt++) {
            int nb = wave * 4 + nt;
            bh[ks][nt] = *(const short8*)(Bhi + ((ks * 16 + nb) * 64 + lane) * 8);
            bl[ks][nt] = *(const short8*)(Blo + ((ks * 16 + nb) * 64 + lane) * 8);
        }
#pragma unroll
    for (int g = 0; g < 4; g++) {
        int mbase = blockIdx.x * 64 + g * 16;
        int ma = mbase + (lane & 15); if (ma >= N) ma = N - 1;
        floatx4 acc[4] = {};
#pragma unroll
        for (int ks = 0; ks < 4; ks++) {
            short8 a = *(const short8*)(A + (size_t)ma * 128 + ks * 32 + quad * 8);
#pragma unroll
            for (int nt = 0; nt < 4; nt++) {
                acc[nt] = __builtin_amdgcn_mfma_f32_16x16x32_bf16(a, bh[ks][nt], acc[nt], 0, 0, 0);
                acc[nt] = __builtin_amdgcn_mfma_f32_16x16x32_bf16(a, bl[ks][nt], acc[nt], 0, 0, 0);
            }
        }
        int md = mbase + quad * 4;
#pragma unroll
        for (int nt = 0; nt < 4; nt++) {
            int n0 = wave * 64 + nt * 16 + (lane & 15);
            float bias = buv[n0];
            unsigned short* dst = (n0 < 128) ? Ub : Vb;
            int cc = n0 & 127;
#pragma unroll
            for (int r = 0; r < 4; r++) {
                int node = md + r;
                if (node < N)
                    dst[(size_t)node * 128 + cc] =
                        (unsigned short)f2bf(acc[nt][r] + bias);
            }
        }
    }
}

// ---------- head: out[q] = relu(Ub[src]+Vb[dst]) . Wc2 + bc2 ----------
__global__ __launch_bounds__(256) void k_head(const unsigned short* __restrict__ Ub,
                                              const unsigned short* __restrict__ Vb,
                                              const int* __restrict__ srcA,
                                              const int* __restrict__ dstA,
                                              const float* __restrict__ Wc2,
                                              const float* __restrict__ bc2,
                                              float* __restrict__ out, int Q) {
    int t = threadIdx.x;
    int q = blockIdx.x * 16 + (t >> 4);
    if (q >= Q) return;
    int l = t & 15;
    int s = srcA[q], d = dstA[q];
    uint4 u = *(const uint4*)(Ub + (size_t)s * 128 + l * 8);
    uint4 v = *(const uint4*)(Vb + (size_t)d * 128 + l * 8);
    const float4* w = (const float4*)(Wc2 + l * 8);
    float4 w0 = w[0], w1 = w[1];
    float acc = 0.f, z;
    z = fmaxf(bf2f(u.x & 0xFFFF) + bf2f(v.x & 0xFFFF), 0.f); acc += z * w0.x;
    z = fmaxf(bf2f(u.x >> 16)    + bf2f(v.x >> 16),    0.f); acc += z * w0.y;
    z = fmaxf(bf2f(u.y & 0xFFFF) + bf2f(v.y & 0xFFFF), 0.f); acc += z * w0.z;
    z = fmaxf(bf2f(u.y >> 16)    + bf2f(v.y >> 16),    0.f); acc += z * w0.w;
    z = fmaxf(bf2f(u.z & 0xFFFF) + bf2f(v.z & 0xFFFF), 0.f); acc += z * w1.x;
    z = fmaxf(bf2f(u.z >> 16)    + bf2f(v.z >> 16),    0.f); acc += z * w1.y;
    z = fmaxf(bf2f(u.w & 0xFFFF) + bf2f(v.w & 0xFFFF), 0.f); acc += z * w1.z;
    z = fmaxf(bf2f(u.w >> 16)    + bf2f(v.w >> 16),    0.f); acc += z * w1.w;
    acc += __shfl_xor(acc, 1);
    acc += __shfl_xor(acc, 2);
    acc += __shfl_xor(acc, 4);
    acc += __shfl_xor(acc, 8);
    if (l == 0) out[q] = acc + bc2[0];
}

extern "C" void kernel_launch(void* const* d_in, const int* in_sizes, int n_in,
                              void* d_out, int out_size, void* d_ws, size_t ws_size,
                              hipStream_t stream) {
    const float* x   = (const float*)d_in[0];
    const int*   ei  = (const int*)d_in[1];
    const int*   eli = (const int*)d_in[2];
    const float* W1  = (const float*)d_in[3];
    const float* b1  = (const float*)d_in[4];
    const float* W2  = (const float*)d_in[5];
    const float* b2  = (const float*)d_in[6];
    const float* Wc1 = (const float*)d_in[7];
    const float* bc1 = (const float*)d_in[8];
    const float* Wc2 = (const float*)d_in[9];
    const float* bc2 = (const float*)d_in[10];
    float* out = (float*)d_out;
    char* wsb = (char*)d_ws;

    const int N = in_sizes[0] / 64;
    const int E = in_sizes[1] / 2;
    const int Q = in_sizes[2] / 2;
    const int W = (N + 1) / 2;
    const int chunk = (E + HB - 1) / HB;
    const int nPass = (N + NWIN - 1) / NWIN;   // fill windows (nodes)
    const int nWinH = (W + NWIN - 1) / NWIN;   // hist windows (words)
    const int nHist = HB * 2 * nWinH;
    const int nXb   = (N * 32 + 255) / 256;

    // workspace layout (word offsets, 4B units); peak ~18.7M words = 74.8 MB
    float* dis       = (float*)wsb;                                // 65536
    int*   offs      = (int*)wsb + 65536;                          // N+1
    int*   bsum      = (int*)wsb + 197120;                         // 256
    int*   cntCol    = (int*)wsb + 197376;                         // 65536
    float* buv       = (float*)wsb + 262912;                       // 256
    unsigned short* UVhi = (unsigned short*)((int*)wsb + 263168);  // 32768 us
    unsigned short* UVlo = (unsigned short*)((int*)wsb + 279552);
    unsigned short* W1hi = (unsigned short*)((int*)wsb + 295936);  // 8192 us
    unsigned short* W1lo = (unsigned short*)((int*)wsb + 300032);
    int*   srcSorted = (int*)wsb + 304128;                         // E -> 1104128
    unsigned short* Vb   = (unsigned short*)((int*)wsb + 1104128); // N*128 us -> 4304128
    unsigned short* h1b  = (unsigned short*)((int*)wsb + 4304128); // N*128 us -> 7504128
    unsigned short* agg2b= (unsigned short*)((int*)wsb + 7504128); // N*128 us -> 10704128
    unsigned short* Ub = h1b;                                      // overlays dead h1b
    unsigned int* hRow = (unsigned int*)wsb + 10704128;            // HB*W -> 13904128
    unsigned int* hCol = (unsigned int*)wsb + 13904128;            // HB*W -> 17104128
    unsigned int* xb   = (unsigned int*)wsb + 17104128;            // N*32 words -> 18704128

    const int* row  = ei;
    const int* col  = ei + E;
    const int* srcA = eli;
    const int* dstA = eli + Q;

    const int scanB = (N + 1023) / 1024;

    k_pre<<<nHist + nXb + 161, 256, 0, stream>>>(
        row, col, hRow, hCol, x, xb, W1, W2, Wc1, b2, bc1,
        UVhi, UVlo, W1hi, W1lo, buv, E, N, W, chunk, nHist, nXb);
    k_reduce<<<(W + 255) / 256, 256, 0, stream>>>(hRow, hCol, cntCol, dis, N, W);
    k_scan1<<<scanB, 256, 0, stream>>>(cntCol, offs, bsum, N);
    k_scan2<<<1, 256, 0, stream>>>(bsum, scanB);
    k_scan3<<<(N + 255) / 256, 256, 0, stream>>>(offs, bsum, N, E);
    k_fill3<<<dim3(HB, nPass), 256, 0, stream>>>(row, col, offs, hCol, srcSorted, E, N, W, chunk);
    k_conv1<<<(N + 63) / 64, 256, 0, stream>>>(
        (const unsigned short*)xb, offs, srcSorted, dis, W1hi, W1lo, b1, h1b, N);
    k_gather2<<<((size_t)N * 16 + 255) / 256, 256, 0, stream>>>(
        h1b, offs, srcSorted, dis, agg2b, N);
    k_mfmaUV<<<(N + 63) / 64, 256, 0, stream>>>(agg2b, UVhi, UVlo, buv, Ub, Vb, N);
    k_head<<<(Q + 15) / 16, 256, 0, stream>>>(Ub, Vb, srcA, dstA, Wc2, bc2, out, Q);
}

// Round 12
// 261.489 us; speedup vs baseline: 1.5062x; 1.0728x over previous
//
#include <hip/hip_runtime.h>

// N=50000, E=800000, Q=200000, d_in=64, h=128
// bf16 random-access features; split-bf16 MFMA; atomic-free CSR build.
// Fusions: hist+xb+fold (k_pre); gather1+mfma1 fused at 16 nodes/block (k_conv1).

#define HB 128      // histogram / fill chunks
#define NWIN 16384  // node/word window (64KB LDS)

typedef __attribute__((ext_vector_type(8))) short short8;
typedef __attribute__((ext_vector_type(4))) float floatx4;

static __device__ __forceinline__ unsigned int f2bf(float v) {
    union { float f; unsigned int u; } c; c.f = v;
    unsigned int lsb = (c.u >> 16) & 1u;
    c.u += 0x7FFFu + lsb;                 // round-to-nearest-even
    return c.u >> 16;
}
static __device__ __forceinline__ float bf2f(unsigned int h) {
    union { float f; unsigned int u; } c; c.u = h << 16;
    return c.f;
}

// ---------- fused prologue: histogram + x->bf16 + weight fold/pack ----------
__global__ __launch_bounds__(256) void k_pre(const int* __restrict__ row,
                                             const int* __restrict__ col,
                                             unsigned int* __restrict__ hRow,
                                             unsigned int* __restrict__ hCol,
                                             const float* __restrict__ x,
                                             unsigned int* __restrict__ xb,
                                             const float* __restrict__ W1,
                                             const float* __restrict__ W2,
                                             const float* __restrict__ Wc1,
                                             const float* __restrict__ b2,
                                             const float* __restrict__ bc1,
                                             unsigned short* __restrict__ UVhi,
                                             unsigned short* __restrict__ UVlo,
                                             unsigned short* __restrict__ W1hi,
                                             unsigned short* __restrict__ W1lo,
                                             float* __restrict__ buv,
                                             int E, int N, int W, int chunk,
                                             int nHist, int nXb) {
    __shared__ unsigned int lds[NWIN];
    int t = threadIdx.x, b = blockIdx.x;
    if (b < nHist) {
        int hb = b % HB;
        int yb = b / HB;
        int p = yb >> 1, win = yb & 1;
        int base = win * NWIN;
        int wcap = min(W - base, NWIN);
        if (wcap <= 0) return;
        const int* idxArr = p ? col : row;
        unsigned int* outArr = p ? hCol : hRow;
        int e0 = hb * chunk, e1 = min(E, e0 + chunk);
        for (int i = t; i < wcap; i += 256) lds[i] = 0;
        __syncthreads();
        for (int e = e0 + t; e < e1; e += 256) {
            int idx = idxArr[e];
            int w = (idx >> 1) - base;
            if ((unsigned)w < (unsigned)wcap)
                atomicAdd(&lds[w], 1u << ((idx & 1) * 16));
        }
        __syncthreads();
        for (int i = t; i < wcap; i += 256)
            outArr[(size_t)hb * W + base + i] = lds[i];
    } else if (b < nHist + nXb) {
        int i = (b - nHist) * 256 + t;
        if (i < N * 32) {
            float2 v = ((const float2*)x)[i];
            xb[i] = f2bf(v.x) | (f2bf(v.y) << 16);
        }
    } else {
        int bf = b - nHist - nXb;
        float* w2row = (float*)lds;
        if (bf < 128) {
            int k = bf;
            int j = t & 127, half = t >> 7;
            int n = half * 128 + j;
            const float* wc = Wc1 + (size_t)half * 128 * 128 + j;
            if (t < 128) w2row[t] = W2[k * 128 + t];
            __syncthreads();
            float acc = 0.f;
#pragma unroll 8
            for (int m = 0; m < 128; m++) acc += w2row[m] * wc[(size_t)m * 128];
            int kstep = k >> 5, kl = k & 31, quad = kl >> 3, j8 = kl & 7;
            int nb = n >> 4, l = quad * 16 + (n & 15);
            int pidx = ((kstep * 16 + nb) * 64 + l) * 8 + j8;
            unsigned int h = f2bf(acc);
            UVhi[pidx] = (unsigned short)h;
            UVlo[pidx] = (unsigned short)f2bf(acc - bf2f(h));
        } else if (bf == 128) {
            int j = t & 127, half = t >> 7;
            const float* wc = Wc1 + (size_t)half * 128 * 128 + j;
            float acc = half ? 0.f : bc1[j];
#pragma unroll 8
            for (int m = 0; m < 128; m++) acc += b2[m] * wc[(size_t)m * 128];
            buv[half * 128 + j] = acc;
        } else {
            int idx = (bf - 129) * 256 + t;  // < 8192
            int k = idx >> 7, n = idx & 127;
            float v = W1[k * 128 + n];
            int kstep = k >> 5, kl = k & 31, quad = kl >> 3, j8 = kl & 7;
            int nb = n >> 4, l = quad * 16 + (n & 15);
            int pidx = ((kstep * 8 + nb) * 64 + l) * 8 + j8;
            unsigned int h = f2bf(v);
            W1hi[pidx] = (unsigned short)h;
            W1lo[pidx] = (unsigned short)f2bf(v - bf2f(h));
        }
    }
}

// Sum 16-bit lanes across HB partials; emit cntCol + dis; REPLACE hCol with
// the exclusive prefix over blocks (packed 16-bit) for k_fill3.
__global__ __launch_bounds__(256) void k_reduce(const unsigned int* __restrict__ hRow,
                                                unsigned int* __restrict__ hCol,
                                                int* __restrict__ cntCol,
                                                float* __restrict__ dis,
                                                int N, int W) {
    int w = blockIdx.x * 256 + threadIdx.x;
    if (w >= W) return;
    unsigned int r0 = 0, r1 = 0, c0 = 0, c1 = 0;
#pragma unroll 8
    for (int b = 0; b < HB; b++) {
        size_t idx = (size_t)b * W + w;
        unsigned int hr = hRow[idx];
        unsigned int hc = hCol[idx];
        hCol[idx] = c0 | (c1 << 16);
        r0 += hr & 0xFFFFu; r1 += hr >> 16;
        c0 += hc & 0xFFFFu; c1 += hc >> 16;
    }
    int n0 = 2 * w, n1 = 2 * w + 1;
    cntCol[n0] = (int)c0;
    dis[n0] = 1.0f / sqrtf((float)(r0 + 1));
    if (n1 < N) {
        cntCol[n1] = (int)c1;
        dis[n1] = 1.0f / sqrtf((float)(r1 + 1));
    }
}

// ---------- scan ----------
__global__ __launch_bounds__(256) void k_scan1(const int* __restrict__ cnt,
                                               int* __restrict__ offs,
                                               int* __restrict__ bsum, int N) {
    __shared__ int ts[256];
    int t = threadIdx.x;
    int base = blockIdx.x * 1024 + t * 4;
    int v0 = (base + 0 < N) ? cnt[base + 0] : 0;
    int v1 = (base + 1 < N) ? cnt[base + 1] : 0;
    int v2 = (base + 2 < N) ? cnt[base + 2] : 0;
    int v3 = (base + 3 < N) ? cnt[base + 3] : 0;
    int sum = v0 + v1 + v2 + v3;
    ts[t] = sum;
    __syncthreads();
    for (int off = 1; off < 256; off <<= 1) {
        int x = (t >= off) ? ts[t - off] : 0;
        __syncthreads();
        ts[t] += x;
        __syncthreads();
    }
    int e = ts[t] - sum;
    if (base + 0 < N) offs[base + 0] = e;
    if (base + 1 < N) offs[base + 1] = e + v0;
    if (base + 2 < N) offs[base + 2] = e + v0 + v1;
    if (base + 3 < N) offs[base + 3] = e + v0 + v1 + v2;
    if (t == 255) bsum[blockIdx.x] = ts[255];
}

__global__ __launch_bounds__(256) void k_scan2(int* __restrict__ bsum, int B) {
    __shared__ int ts[256];
    int t = threadIdx.x;
    int v = (t < B) ? bsum[t] : 0;
    ts[t] = v;
    __syncthreads();
    for (int off = 1; off < 256; off <<= 1) {
        int x = (t >= off) ? ts[t - off] : 0;
        __syncthreads();
        ts[t] += x;
        __syncthreads();
    }
    if (t < B) bsum[t] = ts[t] - v;
}

__global__ __launch_bounds__(256) void k_scan3(int* __restrict__ offs,
                                               const int* __restrict__ bsum,
                                               int N, int E) {
    int i = blockIdx.x * 256 + threadIdx.x;
    if (i < N) offs[i] = offs[i] + bsum[i >> 10];
    if (i == 0) offs[N] = E;
}

// ---------- CSR fill, atomic-free, 2D grid ----------
__global__ __launch_bounds__(256) void k_fill3(const int* __restrict__ row,
                                               const int* __restrict__ col,
                                               const int* __restrict__ offs,
                                               const unsigned int* __restrict__ hCol,
                                               int* __restrict__ srcSorted,
                                               int E, int N, int W, int chunk) {
    __shared__ int base[NWIN];
    int t = threadIdx.x, b = blockIdx.x;
    int n0 = blockIdx.y * NWIN;
    int nCnt = min(NWIN, N - n0);
    int e0 = b * chunk, e1 = min(E, e0 + chunk);
    for (int wl = t; wl * 2 < nCnt; wl += 256) {
        unsigned int pref = hCol[(size_t)b * W + (n0 >> 1) + wl];
        int nn = n0 + wl * 2;
        base[wl * 2] = offs[nn] + (int)(pref & 0xFFFFu);
        if (wl * 2 + 1 < nCnt)
            base[wl * 2 + 1] = offs[nn + 1] + (int)(pref >> 16);
    }
    __syncthreads();
    for (int e = e0 + t; e < e1; e += 256) {
        int c = col[e] - n0;
        if ((unsigned)c < (unsigned)nCnt) {
            int pos = atomicAdd(&base[c], 1);
            srcSorted[pos] = row[e];
        }
    }
}

// ---------- fused conv1: gather(d=64) -> LDS split-bf16 -> MFMA -> h1b ----------
// 16 nodes/block (grid = N/16 = 3125: full gather parallelism).
// LDS rows padded to 72 bf16 (16B-aligned, conflict-free b128 reads).
__global__ __launch_bounds__(256) void k_conv1(const unsigned short* __restrict__ s,
                                               const int* __restrict__ offs,
                                               const int* __restrict__ srcs,
                                               const float* __restrict__ dis,
                                               const unsigned short* __restrict__ Bhi,
                                               const unsigned short* __restrict__ Blo,
                                               const float* __restrict__ b1,
                                               unsigned short* __restrict__ h1b, int N) {
    __shared__ unsigned short Ahi[16][72];
    __shared__ unsigned short Alo[16][72];
    int t = threadIdx.x;
    int lane = t & 63, wave = t >> 6;
    int quad = lane >> 4;
    // B register-resident (independent of gather)
    short8 bh[2][2], bl[2][2];
#pragma unroll
    for (int ks = 0; ks < 2; ks++)
#pragma unroll
        for (int nt = 0; nt < 2; nt++) {
            int nb = wave * 2 + nt;
            bh[ks][nt] = *(const short8*)(Bhi + ((ks * 8 + nb) * 64 + lane) * 8);
            bl[ks][nt] = *(const short8*)(Blo + ((ks * 8 + nb) * 64 + lane) * 8);
        }
    // gather phase: one pass, 16 nodes x 16 lanes
    {
        int nl = t >> 4;
        int node = blockIdx.x * 16 + nl;
        if (node < N) {
            int c4 = (t & 15) * 4;
            int e = offs[node], eEnd = offs[node + 1];
            float dn = dis[node];
            uint2 w = *(const uint2*)(s + (size_t)node * 64 + c4);
            float4 acc;
            acc.x = bf2f(w.x & 0xFFFF) * dn; acc.y = bf2f(w.x >> 16) * dn;
            acc.z = bf2f(w.y & 0xFFFF) * dn; acc.w = bf2f(w.y >> 16) * dn;
            while (e + 1 < eEnd) {
                int sA = srcs[e], sB = srcs[e + 1];
                float dA = dis[sA], dB = dis[sB];
                uint2 vA = *(const uint2*)(s + (size_t)sA * 64 + c4);
                uint2 vB = *(const uint2*)(s + (size_t)sB * 64 + c4);
                acc.x += bf2f(vA.x & 0xFFFF) * dA + bf2f(vB.x & 0xFFFF) * dB;
                acc.y += bf2f(vA.x >> 16) * dA + bf2f(vB.x >> 16) * dB;
                acc.z += bf2f(vA.y & 0xFFFF) * dA + bf2f(vB.y & 0xFFFF) * dB;
                acc.w += bf2f(vA.y >> 16) * dA + bf2f(vB.y >> 16) * dB;
                e += 2;
            }
            if (e < eEnd) {
                int sA = srcs[e];
                float dA = dis[sA];
                uint2 vA = *(const uint2*)(s + (size_t)sA * 64 + c4);
                acc.x += bf2f(vA.x & 0xFFFF) * dA; acc.y += bf2f(vA.x >> 16) * dA;
                acc.z += bf2f(vA.y & 0xFFFF) * dA; acc.w += bf2f(vA.y >> 16) * dA;
            }
            acc.x *= dn; acc.y *= dn; acc.z *= dn; acc.w *= dn;
            unsigned int h0 = f2bf(acc.x), h1 = f2bf(acc.y),
                         h2 = f2bf(acc.z), h3 = f2bf(acc.w);
            uint2 hw; hw.x = h0 | (h1 << 16); hw.y = h2 | (h3 << 16);
            uint2 lw;
            lw.x = f2bf(acc.x - bf2f(h0)) | (f2bf(acc.y - bf2f(h1)) << 16);
            lw.y = f2bf(acc.z - bf2f(h2)) | (f2bf(acc.w - bf2f(h3)) << 16);
            *(uint2*)(&Ahi[nl][c4]) = hw;
            *(uint2*)(&Alo[nl][c4]) = lw;
        }
    }
    __syncthreads();
    // MFMA phase: one 16-row tile; wave w owns cols [w*32, w*32+32)
    int ml = lane & 15;
    floatx4 acc[2] = {};
#pragma unroll
    for (int ks = 0; ks < 2; ks++) {
        short8 ahi = *(const short8*)(&Ahi[ml][ks * 32 + quad * 8]);
        short8 alo = *(const short8*)(&Alo[ml][ks * 32 + quad * 8]);
#pragma unroll
        for (int nt = 0; nt < 2; nt++) {
            acc[nt] = __builtin_amdgcn_mfma_f32_16x16x32_bf16(ahi, bh[ks][nt], acc[nt], 0, 0, 0);
            acc[nt] = __builtin_amdgcn_mfma_f32_16x16x32_bf16(ahi, bl[ks][nt], acc[nt], 0, 0, 0);
            acc[nt] = __builtin_amdgcn_mfma_f32_16x16x32_bf16(alo, bh[ks][nt], acc[nt], 0, 0, 0);
        }
    }
    int md = blockIdx.x * 16 + quad * 4;
#pragma unroll
    for (int nt = 0; nt < 2; nt++) {
        int n0 = (wave * 2 + nt) * 16 + (lane & 15);
        float bias = b1[n0];
#pragma unroll
        for (int r = 0; r < 4; r++) {
            int node = md + r;
            if (node < N)
                h1b[(size_t)node * 128 + n0] =
                    (unsigned short)f2bf(fmaxf(acc[nt][r] + bias, 0.f) * dis[node]);
        }
    }
}

// ---------- conv2 gather: bf16 h1 in, bf16 agg2 out (d=128, 16 lanes/node) ----------
__global__ __launch_bounds__(256) void k_gather2(const unsigned short* __restrict__ s,
                                                 const int* __restrict__ offs,
                                                 const int* __restrict__ srcs,
                                                 const float* __restrict__ dis,
                                                 unsigned short* __restrict__ agg,
                                                 int N) {
    int tid = blockIdx.x * 256 + threadIdx.x;
    int node = tid >> 4;
    if (node >= N) return;
    int c8 = (tid & 15) * 8;
    int e = offs[node], eEnd = offs[node + 1];
    float dn = dis[node];
    uint4 w = *(const uint4*)(s + (size_t)node * 128 + c8);
    float a0 = bf2f(w.x & 0xFFFF), a1 = bf2f(w.x >> 16);
    float a2 = bf2f(w.y & 0xFFFF), a3 = bf2f(w.y >> 16);
    float a4 = bf2f(w.z & 0xFFFF), a5 = bf2f(w.z >> 16);
    float a6 = bf2f(w.w & 0xFFFF), a7 = bf2f(w.w >> 16);
    while (e + 1 < eEnd) {
        int sA = srcs[e], sB = srcs[e + 1];
        uint4 vA = *(const uint4*)(s + (size_t)sA * 128 + c8);
        uint4 vB = *(const uint4*)(s + (size_t)sB * 128 + c8);
        a0 += bf2f(vA.x & 0xFFFF) + bf2f(vB.x & 0xFFFF);
        a1 += bf2f(vA.x >> 16) + bf2f(vB.x >> 16);
        a2 += bf2f(vA.y & 0xFFFF) + bf2f(vB.y & 0xFFFF);
        a3 += bf2f(vA.y >> 16) + bf2f(vB.y >> 16);
        a4 += bf2f(vA.z & 0xFFFF) + bf2f(vB.z & 0xFFFF);
        a5 += bf2f(vA.z >> 16) + bf2f(vB.z >> 16);
        a6 += bf2f(vA.w & 0xFFFF) + bf2f(vB.w & 0xFFFF);
        a7 += bf2f(vA.w >> 16) + bf2f(vB.w >> 16);
        e += 2;
    }
    if (e < eEnd) {
        int sA = srcs[e];
        uint4 vA = *(const uint4*)(s + (size_t)sA * 128 + c8);
        a0 += bf2f(vA.x & 0xFFFF); a1 += bf2f(vA.x >> 16);
        a2 += bf2f(vA.y & 0xFFFF); a3 += bf2f(vA.y >> 16);
        a4 += bf2f(vA.z & 0xFFFF); a5 += bf2f(vA.z >> 16);
        a6 += bf2f(vA.w & 0xFFFF); a7 += bf2f(vA.w >> 16);
    }
    uint4 o;
    o.x = f2bf(a0 * dn) | (f2bf(a1 * dn) << 16);
    o.y = f2bf(a2 * dn) | (f2bf(a3 * dn) << 16);
    o.z = f2bf(a4 * dn) | (f2bf(a5 * dn) << 16);
    o.w = f2bf(a6 * dn) | (f2bf(a7 * dn) << 16);
    *(uint4*)(agg + (size_t)node * 128 + c8) = o;
}

// ---------- MFMA GEMM UV: [Ub|Vb] = bf16(agg2b @ Wfull + buv) ----------
// 64 rows/block, B register-resident (128 VGPR) across 4 row groups.
__global__ __launch_bounds__(256) void k_mfmaUV(const unsigned short* __restrict__ A,
                                                const unsigned short* __restrict__ Bhi,
                                                const unsigned short* __restrict__ Blo,
                                                const float* __restrict__ buv,
                                                unsigned short* __restrict__ Ub,
                                                unsigned short* __restrict__ Vb, int N) {
    int lane = threadIdx.x & 63, wave = threadIdx.x >> 6;
    int quad = lane >> 4;
    short8 bh[4][4], bl[4][4];
#pragma unroll
    for (int ks = 0; ks < 4; ks++)
#pragma unroll
        for (int nt = 0; nt < 4; nt++) {
            int nb = wave * 4 + nt;
            bh[ks][nt] = *(const short8*)(Bhi + ((ks * 16 + nb) * 64 + lane) * 8);
            bl[ks][nt] = *(const short8*)(Blo + ((ks * 16 + nb) * 64 + lane) * 8);
        }
#pragma unroll
    for (int g = 0; g < 4; g++) {
        int mbase = blockIdx.x * 64 + g * 16;
        int ma = mbase + (lane & 15); if (ma >= N) ma = N - 1;
        floatx4 acc[4] = {};
#pragma unroll
        for (int ks = 0; ks < 4; ks++) {
            short8 a = *(const short8*)(A + (size_t)ma * 128 + ks * 32 + quad * 8);
#pragma unroll
            for (int nt = 0; nt < 4; nt++) {
                acc[nt] = __builtin_amdgcn_mfma_f32_16x16x32_bf16(a, bh[ks][nt], acc[nt], 0, 0, 0);
                acc[nt] = __builtin_amdgcn_mfma_f32_16x16x32_bf16(a, bl[ks][nt], acc[nt], 0, 0, 0);
            }
        }
        int md = mbase + quad * 4;
#pragma unroll
        for (int nt = 0; nt < 4; nt++) {
            int n0 = wave * 64 + nt * 16 + (lane & 15);
            float bias = buv[n0];
            unsigned short* dst = (n0 < 128) ? Ub : Vb;
            int cc = n0 & 127;
#pragma unroll
            for (int r = 0; r < 4; r++) {
                int node = md + r;
                if (node < N)
                    dst[(size_t)node * 128 + cc] =
                        (unsigned short)f2bf(acc[nt][r] + bias);
            }
        }
    }
}

// ---------- head: out[q] = relu(Ub[src]+Vb[dst]) . Wc2 + bc2 ----------
__global__ __launch_bounds__(256) void k_head(const unsigned short* __restrict__ Ub,
                                              const unsigned short* __restrict__ Vb,
                                              const int* __restrict__ srcA,
                                              const int* __restrict__ dstA,
                                              const float* __restrict__ Wc2,
                                              const float* __restrict__ bc2,
                                              float* __restrict__ out, int Q) {
    int t = threadIdx.x;
    int q = blockIdx.x * 16 + (t >> 4);
    if (q >= Q) return;
    int l = t & 15;
    int s = srcA[q], d = dstA[q];
    uint4 u = *(const uint4*)(Ub + (size_t)s * 128 + l * 8);
    uint4 v = *(const uint4*)(Vb + (size_t)d * 128 + l * 8);
    const float4* w = (const float4*)(Wc2 + l * 8);
    float4 w0 = w[0], w1 = w[1];
    float acc = 0.f, z;
    z = fmaxf(bf2f(u.x & 0xFFFF) + bf2f(v.x & 0xFFFF), 0.f); acc += z * w0.x;
    z = fmaxf(bf2f(u.x >> 16)    + bf2f(v.x >> 16),    0.f); acc += z * w0.y;
    z = fmaxf(bf2f(u.y & 0xFFFF) + bf2f(v.y & 0xFFFF), 0.f); acc += z * w0.z;
    z = fmaxf(bf2f(u.y >> 16)    + bf2f(v.y >> 16),    0.f); acc += z * w0.w;
    z = fmaxf(bf2f(u.z & 0xFFFF) + bf2f(v.z & 0xFFFF), 0.f); acc += z * w1.x;
    z = fmaxf(bf2f(u.z >> 16)    + bf2f(v.z >> 16),    0.f); acc += z * w1.y;
    z = fmaxf(bf2f(u.w & 0xFFFF) + bf2f(v.w & 0xFFFF), 0.f); acc += z * w1.z;
    z = fmaxf(bf2f(u.w >> 16)    + bf2f(v.w >> 16),    0.f); acc += z * w1.w;
    acc += __shfl_xor(acc, 1);
    acc += __shfl_xor(acc, 2);
    acc += __shfl_xor(acc, 4);
    acc += __shfl_xor(acc, 8);
    if (l == 0) out[q] = acc + bc2[0];
}

extern "C" void kernel_launch(void* const* d_in, const int* in_sizes, int n_in,
                              void* d_out, int out_size, void* d_ws, size_t ws_size,
                              hipStream_t stream) {
    const float* x   = (const float*)d_in[0];
    const int*   ei  = (const int*)d_in[1];
    const int*   eli = (const int*)d_in[2];
    const float* W1  = (const float*)d_in[3];
    const float* b1  = (const float*)d_in[4];
    const float* W2  = (const float*)d_in[5];
    const float* b2  = (const float*)d_in[6];
    const float* Wc1 = (const float*)d_in[7];
    const float* bc1 = (const float*)d_in[8];
    const float* Wc2 = (const float*)d_in[9];
    const float* bc2 = (const float*)d_in[10];
    float* out = (float*)d_out;
    char* wsb = (char*)d_ws;

    const int N = in_sizes[0] / 64;
    const int E = in_sizes[1] / 2;
    const int Q = in_sizes[2] / 2;
    const int W = (N + 1) / 2;
    const int chunk = (E + HB - 1) / HB;
    const int nPass = (N + NWIN - 1) / NWIN;   // fill windows (nodes)
    const int nWinH = (W + NWIN - 1) / NWIN;   // hist windows (words)
    const int nHist = HB * 2 * nWinH;
    const int nXb   = (N * 32 + 255) / 256;

    // workspace layout (word offsets, 4B units); peak ~18.7M words = 74.8 MB
    float* dis       = (float*)wsb;                                // 65536
    int*   offs      = (int*)wsb + 65536;                          // N+1
    int*   bsum      = (int*)wsb + 197120;                         // 256
    int*   cntCol    = (int*)wsb + 197376;                         // 65536
    float* buv       = (float*)wsb + 262912;                       // 256
    unsigned short* UVhi = (unsigned short*)((int*)wsb + 263168);  // 32768 us
    unsigned short* UVlo = (unsigned short*)((int*)wsb + 279552);
    unsigned short* W1hi = (unsigned short*)((int*)wsb + 295936);  // 8192 us
    unsigned short* W1lo = (unsigned short*)((int*)wsb + 300032);
    int*   srcSorted = (int*)wsb + 304128;                         // E -> 1104128
    unsigned short* Vb   = (unsigned short*)((int*)wsb + 1104128); // N*128 us -> 4304128
    unsigned short* h1b  = (unsigned short*)((int*)wsb + 4304128); // N*128 us -> 7504128
    unsigned short* agg2b= (unsigned short*)((int*)wsb + 7504128); // N*128 us -> 10704128
    unsigned short* Ub = h1b;                                      // overlays dead h1b
    unsigned int* hRow = (unsigned int*)wsb + 10704128;            // HB*W -> 13904128
    unsigned int* hCol = (unsigned int*)wsb + 13904128;            // HB*W -> 17104128
    unsigned int* xb   = (unsigned int*)wsb + 17104128;            // N*32 words -> 18704128

    const int* row  = ei;
    const int* col  = ei + E;
    const int* srcA = eli;
    const int* dstA = eli + Q;

    const int scanB = (N + 1023) / 1024;

    k_pre<<<nHist + nXb + 161, 256, 0, stream>>>(
        row, col, hRow, hCol, x, xb, W1, W2, Wc1, b2, bc1,
        UVhi, UVlo, W1hi, W1lo, buv, E, N, W, chunk, nHist, nXb);
    k_reduce<<<(W + 255) / 256, 256, 0, stream>>>(hRow, hCol, cntCol, dis, N, W);
    k_scan1<<<scanB, 256, 0, stream>>>(cntCol, offs, bsum, N);
    k_scan2<<<1, 256, 0, stream>>>(bsum, scanB);
    k_scan3<<<(N + 255) / 256, 256, 0, stream>>>(offs, bsum, N, E);
    k_fill3<<<dim3(HB, nPass), 256, 0, stream>>>(row, col, offs, hCol, srcSorted, E, N, W, chunk);
    k_conv1<<<(N + 15) / 16, 256, 0, stream>>>(
        (const unsigned short*)xb, offs, srcSorted, dis, W1hi, W1lo, b1, h1b, N);
    k_gather2<<<((size_t)N * 16 + 255) / 256, 256, 0, stream>>>(
        h1b, offs, srcSorted, dis, agg2b, N);
    k_mfmaUV<<<(N + 63) / 64, 256, 0, stream>>>(agg2b, UVhi, UVlo, buv, Ub, Vb, N);
    k_head<<<(Q + 15) / 16, 256, 0, stream>>>(Ub, Vb, srcA, dstA, Wc2, bc2, out, Q);
}

// Round 13
// 258.041 us; speedup vs baseline: 1.5263x; 1.0134x over previous
//
#include <hip/hip_runtime.h>

// N=50000, E=800000, Q=200000, d_in=64, h=128
// bf16 random-access features; split-bf16 MFMA; atomic-free CSR build (HB=64);
// fusions: hist+xb+fold (k_pre); reduce+scan1 (k_rs); gather1+mfma1 (k_conv1).

#define HB 64       // histogram / fill chunks
#define NWIN 16384  // node/word window (64KB LDS)

typedef __attribute__((ext_vector_type(8))) short short8;
typedef __attribute__((ext_vector_type(4))) float floatx4;

static __device__ __forceinline__ unsigned int f2bf(float v) {
    union { float f; unsigned int u; } c; c.f = v;
    unsigned int lsb = (c.u >> 16) & 1u;
    c.u += 0x7FFFu + lsb;                 // round-to-nearest-even
    return c.u >> 16;
}
static __device__ __forceinline__ float bf2f(unsigned int h) {
    union { float f; unsigned int u; } c; c.u = h << 16;
    return c.f;
}

// ---------- fused prologue: histogram + x->bf16 + weight fold/pack ----------
__global__ __launch_bounds__(256) void k_pre(const int* __restrict__ row,
                                             const int* __restrict__ col,
                                             unsigned int* __restrict__ hRow,
                                             unsigned int* __restrict__ hCol,
                                             const float* __restrict__ x,
                                             unsigned int* __restrict__ xb,
                                             const float* __restrict__ W1,
                                             const float* __restrict__ W2,
                                             const float* __restrict__ Wc1,
                                             const float* __restrict__ b2,
                                             const float* __restrict__ bc1,
                                             unsigned short* __restrict__ UVhi,
                                             unsigned short* __restrict__ UVlo,
                                             unsigned short* __restrict__ W1hi,
                                             unsigned short* __restrict__ W1lo,
                                             float* __restrict__ buv,
                                             int E, int N, int W, int chunk,
                                             int nHist, int nXb) {
    __shared__ unsigned int lds[NWIN];
    int t = threadIdx.x, b = blockIdx.x;
    if (b < nHist) {
        int hb = b % HB;
        int yb = b / HB;
        int p = yb >> 1, win = yb & 1;
        int base = win * NWIN;
        int wcap = min(W - base, NWIN);
        if (wcap <= 0) return;
        const int* idxArr = p ? col : row;
        unsigned int* outArr = p ? hCol : hRow;
        int e0 = hb * chunk, e1 = min(E, e0 + chunk);
        for (int i = t; i < wcap; i += 256) lds[i] = 0;
        __syncthreads();
        for (int e = e0 + t; e < e1; e += 256) {
            int idx = idxArr[e];
            int w = (idx >> 1) - base;
            if ((unsigned)w < (unsigned)wcap)
                atomicAdd(&lds[w], 1u << ((idx & 1) * 16));
        }
        __syncthreads();
        for (int i = t; i < wcap; i += 256)
            outArr[(size_t)hb * W + base + i] = lds[i];
    } else if (b < nHist + nXb) {
        int i = (b - nHist) * 256 + t;
        if (i < N * 32) {
            float2 v = ((const float2*)x)[i];
            xb[i] = f2bf(v.x) | (f2bf(v.y) << 16);
        }
    } else {
        int bf = b - nHist - nXb;
        float* w2row = (float*)lds;
        if (bf < 128) {
            int k = bf;
            int j = t & 127, half = t >> 7;
            int n = half * 128 + j;
            const float* wc = Wc1 + (size_t)half * 128 * 128 + j;
            if (t < 128) w2row[t] = W2[k * 128 + t];
            __syncthreads();
            float acc = 0.f;
#pragma unroll 8
            for (int m = 0; m < 128; m++) acc += w2row[m] * wc[(size_t)m * 128];
            int kstep = k >> 5, kl = k & 31, quad = kl >> 3, j8 = kl & 7;
            int nb = n >> 4, l = quad * 16 + (n & 15);
            int pidx = ((kstep * 16 + nb) * 64 + l) * 8 + j8;
            unsigned int h = f2bf(acc);
            UVhi[pidx] = (unsigned short)h;
            UVlo[pidx] = (unsigned short)f2bf(acc - bf2f(h));
        } else if (bf == 128) {
            int j = t & 127, half = t >> 7;
            const float* wc = Wc1 + (size_t)half * 128 * 128 + j;
            float acc = half ? 0.f : bc1[j];
#pragma unroll 8
            for (int m = 0; m < 128; m++) acc += b2[m] * wc[(size_t)m * 128];
            buv[half * 128 + j] = acc;
        } else {
            int idx = (bf - 129) * 256 + t;  // < 8192
            int k = idx >> 7, n = idx & 127;
            float v = W1[k * 128 + n];
            int kstep = k >> 5, kl = k & 31, quad = kl >> 3, j8 = kl & 7;
            int nb = n >> 4, l = quad * 16 + (n & 15);
            int pidx = ((kstep * 8 + nb) * 64 + l) * 8 + j8;
            unsigned int h = f2bf(v);
            W1hi[pidx] = (unsigned short)h;
            W1lo[pidx] = (unsigned short)f2bf(v - bf2f(h));
        }
    }
}

// ---------- fused reduce + block-local scan ----------
// Per word w (2 nodes): sum HB partials -> deg(row), cnt(col); replace hCol
// with exclusive prefix over blocks; emit dis; block-scan the 512 node counts
// into block-local offs + bsum[block].  (scan2 + scan3 finish the scan.)
__global__ __launch_bounds__(256) void k_rs(const unsigned int* __restrict__ hRow,
                                            unsigned int* __restrict__ hCol,
                                            float* __restrict__ dis,
                                            int* __restrict__ offs,
                                            int* __restrict__ bsum,
                                            int N, int W) {
    __shared__ int ts[256];
    int t = threadIdx.x;
    int w = blockIdx.x * 256 + t;
    unsigned int r0 = 0, r1 = 0, c0 = 0, c1 = 0;
    if (w < W) {
#pragma unroll 8
        for (int b = 0; b < HB; b++) {
            size_t idx = (size_t)b * W + w;
            unsigned int hr = hRow[idx];
            unsigned int hc = hCol[idx];
            hCol[idx] = c0 | (c1 << 16);   // exclusive prefix over blocks
            r0 += hr & 0xFFFFu; r1 += hr >> 16;
            c0 += hc & 0xFFFFu; c1 += hc >> 16;
        }
        int n0 = 2 * w, n1 = 2 * w + 1;
        dis[n0] = 1.0f / sqrtf((float)(r0 + 1));
        if (n1 < N) dis[n1] = 1.0f / sqrtf((float)(r1 + 1));
    }
    int sum = (w < W) ? (int)(c0 + c1) : 0;
    ts[t] = sum;
    __syncthreads();
    for (int off = 1; off < 256; off <<= 1) {
        int xv = (t >= off) ? ts[t - off] : 0;
        __syncthreads();
        ts[t] += xv;
        __syncthreads();
    }
    int e = ts[t] - sum;  // exclusive within block
    if (w < W) {
        int n0 = 2 * w, n1 = 2 * w + 1;
        offs[n0] = e;
        if (n1 < N) offs[n1] = e + (int)c0;
    }
    if (t == 255) bsum[blockIdx.x] = ts[255];
}

__global__ __launch_bounds__(256) void k_scan2(int* __restrict__ bsum, int B) {
    __shared__ int ts[256];
    int t = threadIdx.x;
    int v = (t < B) ? bsum[t] : 0;
    ts[t] = v;
    __syncthreads();
    for (int off = 1; off < 256; off <<= 1) {
        int x = (t >= off) ? ts[t - off] : 0;
        __syncthreads();
        ts[t] += x;
        __syncthreads();
    }
    if (t < B) bsum[t] = ts[t] - v;
}

// each k_rs block covered 512 nodes -> bsum index = i >> 9
__global__ __launch_bounds__(256) void k_scan3(int* __restrict__ offs,
                                               const int* __restrict__ bsum,
                                               int N, int E) {
    int i = blockIdx.x * 256 + threadIdx.x;
    if (i < N) offs[i] = offs[i] + bsum[i >> 9];
    if (i == 0) offs[N] = E;
}

// ---------- CSR fill, atomic-free, 2D grid ----------
__global__ __launch_bounds__(256) void k_fill3(const int* __restrict__ row,
                                               const int* __restrict__ col,
                                               const int* __restrict__ offs,
                                               const unsigned int* __restrict__ hCol,
                                               int* __restrict__ srcSorted,
                                               int E, int N, int W, int chunk) {
    __shared__ int base[NWIN];
    int t = threadIdx.x, b = blockIdx.x;
    int n0 = blockIdx.y * NWIN;
    int nCnt = min(NWIN, N - n0);
    int e0 = b * chunk, e1 = min(E, e0 + chunk);
    for (int wl = t; wl * 2 < nCnt; wl += 256) {
        unsigned int pref = hCol[(size_t)b * W + (n0 >> 1) + wl];
        int nn = n0 + wl * 2;
        base[wl * 2] = offs[nn] + (int)(pref & 0xFFFFu);
        if (wl * 2 + 1 < nCnt)
            base[wl * 2 + 1] = offs[nn + 1] + (int)(pref >> 16);
    }
    __syncthreads();
    for (int e = e0 + t; e < e1; e += 256) {
        int c = col[e] - n0;
        if ((unsigned)c < (unsigned)nCnt) {
            int pos = atomicAdd(&base[c], 1);
            srcSorted[pos] = row[e];
        }
    }
}

// ---------- fused conv1: gather(d=64) -> LDS split-bf16 -> MFMA -> h1b ----------
// 16 nodes/block (grid = N/16: full gather parallelism).
__global__ __launch_bounds__(256) void k_conv1(const unsigned short* __restrict__ s,
                                               const int* __restrict__ offs,
                                               const int* __restrict__ srcs,
                                               const float* __restrict__ dis,
                                               const unsigned short* __restrict__ Bhi,
                                               const unsigned short* __restrict__ Blo,
                                               const float* __restrict__ b1,
                                               unsigned short* __restrict__ h1b, int N) {
    __shared__ unsigned short Ahi[16][72];
    __shared__ unsigned short Alo[16][72];
    int t = threadIdx.x;
    int lane = t & 63, wave = t >> 6;
    int quad = lane >> 4;
    short8 bh[2][2], bl[2][2];
#pragma unroll
    for (int ks = 0; ks < 2; ks++)
#pragma unroll
        for (int nt = 0; nt < 2; nt++) {
            int nb = wave * 2 + nt;
            bh[ks][nt] = *(const short8*)(Bhi + ((ks * 8 + nb) * 64 + lane) * 8);
            bl[ks][nt] = *(const short8*)(Blo + ((ks * 8 + nb) * 64 + lane) * 8);
        }
    {
        int nl = t >> 4;
        int node = blockIdx.x * 16 + nl;
        if (node < N) {
            int c4 = (t & 15) * 4;
            int e = offs[node], eEnd = offs[node + 1];
            float dn = dis[node];
            uint2 w = *(const uint2*)(s + (size_t)node * 64 + c4);
            float4 acc;
            acc.x = bf2f(w.x & 0xFFFF) * dn; acc.y = bf2f(w.x >> 16) * dn;
            acc.z = bf2f(w.y & 0xFFFF) * dn; acc.w = bf2f(w.y >> 16) * dn;
            while (e + 1 < eEnd) {
                int sA = srcs[e], sB = srcs[e + 1];
                float dA = dis[sA], dB = dis[sB];
                uint2 vA = *(const uint2*)(s + (size_t)sA * 64 + c4);
                uint2 vB = *(const uint2*)(s + (size_t)sB * 64 + c4);
                acc.x += bf2f(vA.x & 0xFFFF) * dA + bf2f(vB.x & 0xFFFF) * dB;
                acc.y += bf2f(vA.x >> 16) * dA + bf2f(vB.x >> 16) * dB;
                acc.z += bf2f(vA.y & 0xFFFF) * dA + bf2f(vB.y & 0xFFFF) * dB;
                acc.w += bf2f(vA.y >> 16) * dA + bf2f(vB.y >> 16) * dB;
                e += 2;
            }
            if (e < eEnd) {
                int sA = srcs[e];
                float dA = dis[sA];
                uint2 vA = *(const uint2*)(s + (size_t)sA * 64 + c4);
                acc.x += bf2f(vA.x & 0xFFFF) * dA; acc.y += bf2f(vA.x >> 16) * dA;
                acc.z += bf2f(vA.y & 0xFFFF) * dA; acc.w += bf2f(vA.y >> 16) * dA;
            }
            acc.x *= dn; acc.y *= dn; acc.z *= dn; acc.w *= dn;
            unsigned int h0 = f2bf(acc.x), h1 = f2bf(acc.y),
                         h2 = f2bf(acc.z), h3 = f2bf(acc.w);
            uint2 hw; hw.x = h0 | (h1 << 16); hw.y = h2 | (h3 << 16);
            uint2 lw;
            lw.x = f2bf(acc.x - bf2f(h0)) | (f2bf(acc.y - bf2f(h1)) << 16);
            lw.y = f2bf(acc.z - bf2f(h2)) | (f2bf(acc.w - bf2f(h3)) << 16);
            *(uint2*)(&Ahi[nl][c4]) = hw;
            *(uint2*)(&Alo[nl][c4]) = lw;
        }
    }
    __syncthreads();
    int ml = lane & 15;
    floatx4 acc[2] = {};
#pragma unroll
    for (int ks = 0; ks < 2; ks++) {
        short8 ahi = *(const short8*)(&Ahi[ml][ks * 32 + quad * 8]);
        short8 alo = *(const short8*)(&Alo[ml][ks * 32 + quad * 8]);
#pragma unroll
        for (int nt = 0; nt < 2; nt++) {
            acc[nt] = __builtin_amdgcn_mfma_f32_16x16x32_bf16(ahi, bh[ks][nt], acc[nt], 0, 0, 0);
            acc[nt] = __builtin_amdgcn_mfma_f32_16x16x32_bf16(ahi, bl[ks][nt], acc[nt], 0, 0, 0);
            acc[nt] = __builtin_amdgcn_mfma_f32_16x16x32_bf16(alo, bh[ks][nt], acc[nt], 0, 0, 0);
        }
    }
    int md = blockIdx.x * 16 + quad * 4;
#pragma unroll
    for (int nt = 0; nt < 2; nt++) {
        int n0 = (wave * 2 + nt) * 16 + (lane & 15);
        float bias = b1[n0];
#pragma unroll
        for (int r = 0; r < 4; r++) {
            int node = md + r;
            if (node < N)
                h1b[(size_t)node * 128 + n0] =
                    (unsigned short)f2bf(fmaxf(acc[nt][r] + bias, 0.f) * dis[node]);
        }
    }
}

// ---------- conv2 gather: bf16 h1 in, bf16 agg2 out (d=128, 16 lanes/node) ----------
__global__ __launch_bounds__(256) void k_gather2(const unsigned short* __restrict__ s,
                                                 const int* __restrict__ offs,
                                                 const int* __restrict__ srcs,
                                                 const float* __restrict__ dis,
                                                 unsigned short* __restrict__ agg,
                                                 int N) {
    int tid = blockIdx.x * 256 + threadIdx.x;
    int node = tid >> 4;
    if (node >= N) return;
    int c8 = (tid & 15) * 8;
    int e = offs[node], eEnd = offs[node + 1];
    float dn = dis[node];
    uint4 w = *(const uint4*)(s + (size_t)node * 128 + c8);
    float a0 = bf2f(w.x & 0xFFFF), a1 = bf2f(w.x >> 16);
    float a2 = bf2f(w.y & 0xFFFF), a3 = bf2f(w.y >> 16);
    float a4 = bf2f(w.z & 0xFFFF), a5 = bf2f(w.z >> 16);
    float a6 = bf2f(w.w & 0xFFFF), a7 = bf2f(w.w >> 16);
    while (e + 1 < eEnd) {
        int sA = srcs[e], sB = srcs[e + 1];
        uint4 vA = *(const uint4*)(s + (size_t)sA * 128 + c8);
        uint4 vB = *(const uint4*)(s + (size_t)sB * 128 + c8);
        a0 += bf2f(vA.x & 0xFFFF) + bf2f(vB.x & 0xFFFF);
        a1 += bf2f(vA.x >> 16) + bf2f(vB.x >> 16);
        a2 += bf2f(vA.y & 0xFFFF) + bf2f(vB.y & 0xFFFF);
        a3 += bf2f(vA.y >> 16) + bf2f(vB.y >> 16);
        a4 += bf2f(vA.z & 0xFFFF) + bf2f(vB.z & 0xFFFF);
        a5 += bf2f(vA.z >> 16) + bf2f(vB.z >> 16);
        a6 += bf2f(vA.w & 0xFFFF) + bf2f(vB.w & 0xFFFF);
        a7 += bf2f(vA.w >> 16) + bf2f(vB.w >> 16);
        e += 2;
    }
    if (e < eEnd) {
        int sA = srcs[e];
        uint4 vA = *(const uint4*)(s + (size_t)sA * 128 + c8);
        a0 += bf2f(vA.x & 0xFFFF); a1 += bf2f(vA.x >> 16);
        a2 += bf2f(vA.y & 0xFFFF); a3 += bf2f(vA.y >> 16);
        a4 += bf2f(vA.z & 0xFFFF); a5 += bf2f(vA.z >> 16);
        a6 += bf2f(vA.w & 0xFFFF); a7 += bf2f(vA.w >> 16);
    }
    uint4 o;
    o.x = f2bf(a0 * dn) | (f2bf(a1 * dn) << 16);
    o.y = f2bf(a2 * dn) | (f2bf(a3 * dn) << 16);
    o.z = f2bf(a4 * dn) | (f2bf(a5 * dn) << 16);
    o.w = f2bf(a6 * dn) | (f2bf(a7 * dn) << 16);
    *(uint4*)(agg + (size_t)node * 128 + c8) = o;
}

// ---------- MFMA GEMM UV: [Ub|Vb] = bf16(agg2b @ Wfull + buv) ----------
__global__ __launch_bounds__(256) void k_mfmaUV(const unsigned short* __restrict__ A,
                                                const unsigned short* __restrict__ Bhi,
                                                const unsigned short* __restrict__ Blo,
                                                const float* __restrict__ buv,
                                                unsigned short* __restrict__ Ub,
                                                unsigned short* __restrict__ Vb, int N) {
    int lane = threadIdx.x & 63, wave = threadIdx.x >> 6;
    int quad = lane >> 4;
    short8 bh[4][4], bl[4][4];
#pragma unroll
    for (int ks = 0; ks < 4; ks++)
#pragma unroll
        for (int nt = 0; nt < 4; nt++) {
            int nb = wave * 4 + nt;
            bh[ks][nt] = *(const short8*)(Bhi + ((ks * 16 + nb) * 64 + lane) * 8);
            bl[ks][nt] = *(const short8*)(Blo + ((ks * 16 + nb) * 64 + lane) * 8);
        }
#pragma unroll
    for (int g = 0; g < 4; g++) {
        int mbase = blockIdx.x * 64 + g * 16;
        int ma = mbase + (lane & 15); if (ma >= N) ma = N - 1;
        floatx4 acc[4] = {};
#pragma unroll
        for (int ks = 0; ks < 4; ks++) {
            short8 a = *(const short8*)(A + (size_t)ma * 128 + ks * 32 + quad * 8);
#pragma unroll
            for (int nt = 0; nt < 4; nt++) {
                acc[nt] = __builtin_amdgcn_mfma_f32_16x16x32_bf16(a, bh[ks][nt], acc[nt], 0, 0, 0);
                acc[nt] = __builtin_amdgcn_mfma_f32_16x16x32_bf16(a, bl[ks][nt], acc[nt], 0, 0, 0);
            }
        }
        int md = mbase + quad * 4;
#pragma unroll
        for (int nt = 0; nt < 4; nt++) {
            int n0 = wave * 64 + nt * 16 + (lane & 15);
            float bias = buv[n0];
            unsigned short* dst = (n0 < 128) ? Ub : Vb;
            int cc = n0 & 127;
#pragma unroll
            for (int r = 0; r < 4; r++) {
                int node = md + r;
                if (node < N)
                    dst[(size_t)node * 128 + cc] =
                        (unsigned short)f2bf(acc[nt][r] + bias);
            }
        }
    }
}

// ---------- head: out[q] = relu(Ub[src]+Vb[dst]) . Wc2 + bc2 ----------
__global__ __launch_bounds__(256) void k_head(const unsigned short* __restrict__ Ub,
                                              const unsigned short* __restrict__ Vb,
                                              const int* __restrict__ srcA,
                                              const int* __restrict__ dstA,
                                              const float* __restrict__ Wc2,
                                              const float* __restrict__ bc2,
                                              float* __restrict__ out, int Q) {
    int t = threadIdx.x;
    int q = blockIdx.x * 16 + (t >> 4);
    if (q >= Q) return;
    int l = t & 15;
    int s = srcA[q], d = dstA[q];
    uint4 u = *(const uint4*)(Ub + (size_t)s * 128 + l * 8);
    uint4 v = *(const uint4*)(Vb + (size_t)d * 128 + l * 8);
    const float4* w = (const float4*)(Wc2 + l * 8);
    float4 w0 = w[0], w1 = w[1];
    float acc = 0.f, z;
    z = fmaxf(bf2f(u.x & 0xFFFF) + bf2f(v.x & 0xFFFF), 0.f); acc += z * w0.x;
    z = fmaxf(bf2f(u.x >> 16)    + bf2f(v.x >> 16),    0.f); acc += z * w0.y;
    z = fmaxf(bf2f(u.y & 0xFFFF) + bf2f(v.y & 0xFFFF), 0.f); acc += z * w0.z;
    z = fmaxf(bf2f(u.y >> 16)    + bf2f(v.y >> 16),    0.f); acc += z * w0.w;
    z = fmaxf(bf2f(u.z & 0xFFFF) + bf2f(v.z & 0xFFFF), 0.f); acc += z * w1.x;
    z = fmaxf(bf2f(u.z >> 16)    + bf2f(v.z >> 16),    0.f); acc += z * w1.y;
    z = fmaxf(bf2f(u.w & 0xFFFF) + bf2f(v.w & 0xFFFF), 0.f); acc += z * w1.z;
    z = fmaxf(bf2f(u.w >> 16)    + bf2f(v.w >> 16),    0.f); acc += z * w1.w;
    acc += __shfl_xor(acc, 1);
    acc += __shfl_xor(acc, 2);
    acc += __shfl_xor(acc, 4);
    acc += __shfl_xor(acc, 8);
    if (l == 0) out[q] = acc + bc2[0];
}

extern "C" void kernel_launch(void* const* d_in, const int* in_sizes, int n_in,
                              void* d_out, int out_size, void* d_ws, size_t ws_size,
                              hipStream_t stream) {
    const float* x   = (const float*)d_in[0];
    const int*   ei  = (const int*)d_in[1];
    const int*   eli = (const int*)d_in[2];
    const float* W1  = (const float*)d_in[3];
    const float* b1  = (const float*)d_in[4];
    const float* W2  = (const float*)d_in[5];
    const float* b2  = (const float*)d_in[6];
    const float* Wc1 = (const float*)d_in[7];
    const float* bc1 = (const float*)d_in[8];
    const float* Wc2 = (const float*)d_in[9];
    const float* bc2 = (const float*)d_in[10];
    float* out = (float*)d_out;
    char* wsb = (char*)d_ws;

    const int N = in_sizes[0] / 64;
    const int E = in_sizes[1] / 2;
    const int Q = in_sizes[2] / 2;
    const int W = (N + 1) / 2;
    const int chunk = (E + HB - 1) / HB;
    const int nPass = (N + NWIN - 1) / NWIN;   // fill windows (nodes)
    const int nWinH = (W + NWIN - 1) / NWIN;   // hist windows (words)
    const int nHist = HB * 2 * nWinH;
    const int nXb   = (N * 32 + 255) / 256;
    const int rsB   = (W + 255) / 256;         // k_rs blocks (512 nodes each)

    // workspace layout (word offsets, 4B units)
    float* dis       = (float*)wsb;                                // 65536
    int*   offs      = (int*)wsb + 65536;                          // N+1
    int*   bsum      = (int*)wsb + 197120;                         // 256
    float* buv       = (float*)wsb + 262912;                       // 256
    unsigned short* UVhi = (unsigned short*)((int*)wsb + 263168);  // 32768 us
    unsigned short* UVlo = (unsigned short*)((int*)wsb + 279552);
    unsigned short* W1hi = (unsigned short*)((int*)wsb + 295936);  // 8192 us
    unsigned short* W1lo = (unsigned short*)((int*)wsb + 300032);
    int*   srcSorted = (int*)wsb + 304128;                         // E -> 1104128
    unsigned short* Vb   = (unsigned short*)((int*)wsb + 1104128); // N*128 us -> 4304128
    unsigned short* h1b  = (unsigned short*)((int*)wsb + 4304128); // N*128 us -> 7504128
    unsigned short* agg2b= (unsigned short*)((int*)wsb + 7504128); // N*128 us -> 10704128
    unsigned short* Ub = h1b;                                      // overlays dead h1b
    unsigned int* hRow = (unsigned int*)wsb + 10704128;            // HB*W -> 12304128
    unsigned int* hCol = (unsigned int*)wsb + 12304128;            // HB*W -> 13904128
    unsigned int* xb   = (unsigned int*)wsb + 13904128;            // N*32 words -> 15504128

    const int* row  = ei;
    const int* col  = ei + E;
    const int* srcA = eli;
    const int* dstA = eli + Q;

    k_pre<<<nHist + nXb + 161, 256, 0, stream>>>(
        row, col, hRow, hCol, x, xb, W1, W2, Wc1, b2, bc1,
        UVhi, UVlo, W1hi, W1lo, buv, E, N, W, chunk, nHist, nXb);
    k_rs<<<rsB, 256, 0, stream>>>(hRow, hCol, dis, offs, bsum, N, W);
    k_scan2<<<1, 256, 0, stream>>>(bsum, rsB);
    k_scan3<<<(N + 255) / 256, 256, 0, stream>>>(offs, bsum, N, E);
    k_fill3<<<dim3(HB, nPass), 256, 0, stream>>>(row, col, offs, hCol, srcSorted, E, N, W, chunk);
    k_conv1<<<(N + 15) / 16, 256, 0, stream>>>(
        (const unsigned short*)xb, offs, srcSorted, dis, W1hi, W1lo, b1, h1b, N);
    k_gather2<<<((size_t)N * 16 + 255) / 256, 256, 0, stream>>>(
        h1b, offs, srcSorted, dis, agg2b, N);
    k_mfmaUV<<<(N + 63) / 64, 256, 0, stream>>>(agg2b, UVhi, UVlo, buv, Ub, Vb, N);
    k_head<<<(Q + 15) / 16, 256, 0, stream>>>(Ub, Vb, srcA, dstA, Wc2, bc2, out, Q);
}